// Round 13
// baseline (271.621 us; speedup 1.0000x reference)
//
#include <hip/hip_runtime.h>
#include <hip/hip_bf16.h>

#define HID 128
#define NBUK 4096

typedef __attribute__((ext_vector_type(8))) short short8;
typedef __attribute__((ext_vector_type(4))) float f32x4;
typedef __attribute__((ext_vector_type(16))) float f32x16;
typedef __attribute__((ext_vector_type(4))) unsigned int u32x4;
typedef __attribute__((ext_vector_type(4))) int i32x4;
typedef __attribute__((ext_vector_type(2))) _Float16 h2;

__device__ __forceinline__ short f2bf(float x) {
    __bf16 b = (__bf16)x;
    return __builtin_bit_cast(short, b);
}

// ===========================================================================
// FACTORED PATH: U = emb@W1[:128], V = emb@W1[128:] (dense per-node GEMM),
// then out[e] = relu(U[src]+V[tgt]+b1)@W2 + b2 (gather + packed-fp16 VALU).
// NEW in R13: counting-sort edges by src (4096 buckets) so U-gathers get
// L1/L2 temporal locality; chunked XCD swizzle keeps buckets on one L2.
// ===========================================================================

// ---------------------------------------------------------------------------
// Pack W1 halves into 32x32x16 MFMA-B fragment order (bf16), both halves.
// ---------------------------------------------------------------------------
__global__ void pack_w1_uv_kernel(const float* __restrict__ W1, short* __restrict__ bpk2) {
    int t = blockIdx.x * 256 + threadIdx.x;   // 0..4095 = half*2048 + nt*512 + ks*64 + l
    int l    = t & 63;
    int ks   = (t >> 6) & 7;
    int nt   = (t >> 9) & 3;
    int half = t >> 11;
    int k0  = half * 128 + ks * 16 + (l >> 5) * 8;
    int col = nt * 32 + (l & 31);
    short8 v;
#pragma unroll
    for (int j = 0; j < 8; ++j)
        v[j] = f2bf(W1[(k0 + j) * HID + col]);
    *reinterpret_cast<short8*>(&bpk2[t * 8]) = v;
}

// ---------------------------------------------------------------------------
// UV precompute (fp16 output): mfma_f32_32x32x16_bf16, 128 nodes/block.
// ---------------------------------------------------------------------------
__global__ __launch_bounds__(512, 4) void uv_kernel(
    const float* __restrict__ emb,
    const short* __restrict__ bpk2,
    unsigned short* __restrict__ U,
    unsigned short* __restrict__ V,
    int Nn)
{
    __shared__ short lds_b[32768];

    const int tid = threadIdx.x;
    const int l   = tid & 63;
    const int wid = tid >> 6;
    const int wg  = wid >> 1;
    const int wn  = wid & 1;
    const int lc  = l & 31;
    const int hi  = l >> 5;

    {
        const u32x4* g = (const u32x4*)bpk2;
        u32x4* d = (u32x4*)lds_b;
#pragma unroll
        for (int i = 0; i < 8; ++i) d[i * 512 + tid] = g[i * 512 + tid];
    }
    __syncthreads();

    const int base = blockIdx.x * 128 + wg * 32;
    int nr = base + lc;
    if (nr >= Nn) nr = Nn - 1;

    f32x16 accU[2], accV[2];
#pragma unroll
    for (int n = 0; n < 2; ++n) { accU[n] = (f32x16)(0.f); accV[n] = (f32x16)(0.f); }

#pragma unroll
    for (int ks = 0; ks < 8; ++ks) {
        const float* p = emb + (size_t)nr * HID + ks * 16 + hi * 8;
        f32x4 x0 = *reinterpret_cast<const f32x4*>(p);
        f32x4 x1 = *reinterpret_cast<const f32x4*>(p + 4);
        short8 afr;
#pragma unroll
        for (int j = 0; j < 4; ++j) { afr[j] = f2bf(x0[j]); afr[4 + j] = f2bf(x1[j]); }
#pragma unroll
        for (int n = 0; n < 2; ++n) {
            const int nt = wn * 2 + n;
            short8 bU = *reinterpret_cast<const short8*>(&lds_b[(((0 + nt) * 8 + ks) * 64 + l) * 8]);
            short8 bV = *reinterpret_cast<const short8*>(&lds_b[(((4 + nt) * 8 + ks) * 64 + l) * 8]);
            accU[n] = __builtin_amdgcn_mfma_f32_32x32x16_bf16(afr, bU, accU[n], 0, 0, 0);
            accV[n] = __builtin_amdgcn_mfma_f32_32x32x16_bf16(afr, bV, accV[n], 0, 0, 0);
        }
    }

#pragma unroll
    for (int n = 0; n < 2; ++n) {
        const int col = wn * 64 + n * 32 + lc;
#pragma unroll
        for (int r = 0; r < 16; ++r) {
            const int row = (r & 3) + 8 * (r >> 2) + 4 * hi;
            const int node = base + row;
            if (node < Nn) {
                _Float16 hu = (_Float16)accU[n][r];
                _Float16 hv = (_Float16)accV[n][r];
                U[(size_t)node * HID + col] = __builtin_bit_cast(unsigned short, hu);
                V[(size_t)node * HID + col] = __builtin_bit_cast(unsigned short, hv);
            }
        }
    }
}

// ---------------------------------------------------------------------------
// Sort pipeline: zero hist -> LDS histogram -> scan -> atomic scatter.
// Output values are order-independent, so atomic nondeterminism is safe.
// ---------------------------------------------------------------------------
__global__ void zero_hist_kernel(int* __restrict__ gh) {
    gh[blockIdx.x * 256 + threadIdx.x] = 0;          // grid 16 x 256 = 4096
}

__global__ __launch_bounds__(256) void hist_kernel(
    const void* __restrict__ src_raw, int E, int shift, int* __restrict__ gh)
{
    __shared__ int lh[NBUK];
    const int tid = threadIdx.x;
    for (int i = tid; i < NBUK; i += 256) lh[i] = 0;
    __syncthreads();

    int i64f = 1;
    {
        const int* s32 = (const int*)src_raw;
#pragma unroll
        for (int i = 1; i < 32; i += 2) i64f &= (s32[i] == 0);
    }
    const int stride = gridDim.x * 256;
    for (int e = blockIdx.x * 256 + tid; e < E; e += stride) {
        int s = i64f ? (int)((const long long*)src_raw)[e]
                     : ((const int*)src_raw)[e];
        atomicAdd(&lh[s >> shift], 1);
    }
    __syncthreads();
    for (int i = tid; i < NBUK; i += 256)
        if (lh[i]) atomicAdd(&gh[i], lh[i]);
}

__global__ __launch_bounds__(1024) void scan_kernel(
    int* __restrict__ gh, int* __restrict__ cursor)
{
    __shared__ int buf[1024];
    const int tid = threadIdx.x;
    i32x4 v = *reinterpret_cast<const i32x4*>(&gh[tid * 4]);
    int s = v[0] + v[1] + v[2] + v[3];
    buf[tid] = s;
    __syncthreads();
#pragma unroll
    for (int off = 1; off < 1024; off <<= 1) {
        int x = (tid >= off) ? buf[tid - off] : 0;
        __syncthreads();
        buf[tid] += x;
        __syncthreads();
    }
    int excl = buf[tid] - s;
    i32x4 o;
    o[0] = excl;
    o[1] = o[0] + v[0];
    o[2] = o[1] + v[1];
    o[3] = o[2] + v[2];
    *reinterpret_cast<i32x4*>(&cursor[tid * 4]) = o;
}

__global__ __launch_bounds__(256) void scatter_kernel(
    const void* __restrict__ src_raw, const void* __restrict__ tgt_raw,
    int E, int shift, int* __restrict__ cursor,
    int* __restrict__ ss, int* __restrict__ tt, int* __restrict__ ei)
{
    int i64f = 1;
    {
        const int* s32 = (const int*)src_raw;
#pragma unroll
        for (int i = 1; i < 32; i += 2) i64f &= (s32[i] == 0);
    }
    const int stride = gridDim.x * 256;
    for (int e = blockIdx.x * 256 + threadIdx.x; e < E; e += stride) {
        int s, t;
        if (i64f) {
            s = (int)((const long long*)src_raw)[e];
            t = (int)((const long long*)tgt_raw)[e];
        } else {
            s = ((const int*)src_raw)[e];
            t = ((const int*)tgt_raw)[e];
        }
        int pos = atomicAdd(&cursor[s >> shift], 1);
        ss[pos] = s;
        tt[pos] = t;
        ei[pos] = e;
    }
}

// ---------------------------------------------------------------------------
// Sorted edge pass: edges arrive bucket-major (by src) -> U rows L1/L2-hot.
// Chunked bijective XCD swizzle (m204) keeps consecutive blocks (same
// buckets) on one XCD's L2. fp16 packed math as in R12.
// ---------------------------------------------------------------------------
__global__ __launch_bounds__(256) void edge_pass_sorted_kernel(
    const unsigned short* __restrict__ U,
    const unsigned short* __restrict__ V,
    const int* __restrict__ ss,
    const int* __restrict__ tt,
    const int* __restrict__ ei,
    const float* __restrict__ b1,
    const float* __restrict__ W2,
    const float* __restrict__ b2,
    float* __restrict__ out,
    int E)
{
    // bijective chunked XCD swizzle
    const int nwg  = gridDim.x;
    const int orig = blockIdx.x;
    const int q = nwg >> 3, r = nwg & 7;
    const int xcd = orig & 7, sub = orig >> 3;
    const int bid = (xcd < r ? xcd * (q + 1) : r * (q + 1) + (xcd - r) * q) + sub;

    const int tid = threadIdx.x;
    const int l   = tid & 63;
    const int wid = tid >> 6;
    const int le  = l >> 4;          // edge slot in group (0..3)
    const int lc  = l & 15;          // col group: cols [lc*8, lc*8+8)

    h2 b1p[4], w2p[4];
    {
        f32x4 a = *reinterpret_cast<const f32x4*>(b1 + lc * 8);
        f32x4 b = *reinterpret_cast<const f32x4*>(b1 + lc * 8 + 4);
        f32x4 c = *reinterpret_cast<const f32x4*>(W2 + lc * 8);
        f32x4 d = *reinterpret_cast<const f32x4*>(W2 + lc * 8 + 4);
#pragma unroll
        for (int j = 0; j < 2; ++j) {
            b1p[0][j] = (_Float16)a[j];     b1p[1][j] = (_Float16)a[2 + j];
            b1p[2][j] = (_Float16)b[j];     b1p[3][j] = (_Float16)b[2 + j];
            w2p[0][j] = (_Float16)c[j];     w2p[1][j] = (_Float16)c[2 + j];
            w2p[2][j] = (_Float16)d[j];     w2p[3][j] = (_Float16)d[2 + j];
        }
    }
    const float b2s = b2[0];
    const h2 zero2 = (h2)((_Float16)0.f);

    const int ebase = (bid * 4 + wid) * 16;

    short8 ub[4], vb[4];
    int oid[4];
    bool live[4];
#pragma unroll
    for (int g = 0; g < 4; ++g) {
        int pos = ebase + g * 4 + le;
        live[g] = (pos < E);
        if (pos >= E) pos = E - 1;
        const int s = ss[pos];
        const int t = tt[pos];
        oid[g] = ei[pos];
        ub[g] = *reinterpret_cast<const short8*>(U + (unsigned)s * HID + lc * 8);
        vb[g] = *reinterpret_cast<const short8*>(V + (unsigned)t * HID + lc * 8);
    }

#pragma unroll
    for (int g = 0; g < 4; ++g) {
        const unsigned int* uw = (const unsigned int*)&ub[g];
        const unsigned int* vw = (const unsigned int*)&vb[g];
        h2 s2 = zero2;
#pragma unroll
        for (int j = 0; j < 4; ++j) {
            h2 hu = __builtin_bit_cast(h2, uw[j]);
            h2 hv = __builtin_bit_cast(h2, vw[j]);
            h2 h  = hu + hv + b1p[j];
            h = __builtin_elementwise_max(h, zero2);
            s2 = s2 + h * w2p[j];
        }
        float s = (float)s2[0] + (float)s2[1];
#pragma unroll
        for (int w = 1; w < 16; w <<= 1)
            s += __shfl_xor(s, w, 16);
        if (lc == 0 && live[g])
            out[oid[g]] = s + b2s;
    }
}

// ---------------------------------------------------------------------------
// Unsorted edge pass (R12 path, fallback when ws can't hold sort arrays).
// ---------------------------------------------------------------------------
__global__ __launch_bounds__(256) void edge_pass_kernel(
    const unsigned short* __restrict__ U,
    const unsigned short* __restrict__ V,
    const void* __restrict__ src_raw,
    const void* __restrict__ tgt_raw,
    const float* __restrict__ b1,
    const float* __restrict__ W2,
    const float* __restrict__ b2,
    float* __restrict__ out,
    int E)
{
    const int tid = threadIdx.x;
    const int l   = tid & 63;
    const int wid = tid >> 6;
    const int le  = l >> 4;
    const int lc  = l & 15;

    int oddw = 0;
    {
        const int* s32 = (const int*)src_raw;
        if (l < 32) oddw = s32[2 * l + 1];
    }
    const bool i64f = (__ballot(oddw != 0) == 0ULL);

    h2 b1p[4], w2p[4];
    {
        f32x4 a = *reinterpret_cast<const f32x4*>(b1 + lc * 8);
        f32x4 b = *reinterpret_cast<const f32x4*>(b1 + lc * 8 + 4);
        f32x4 c = *reinterpret_cast<const f32x4*>(W2 + lc * 8);
        f32x4 d = *reinterpret_cast<const f32x4*>(W2 + lc * 8 + 4);
#pragma unroll
        for (int j = 0; j < 2; ++j) {
            b1p[0][j] = (_Float16)a[j];     b1p[1][j] = (_Float16)a[2 + j];
            b1p[2][j] = (_Float16)b[j];     b1p[3][j] = (_Float16)b[2 + j];
            w2p[0][j] = (_Float16)c[j];     w2p[1][j] = (_Float16)c[2 + j];
            w2p[2][j] = (_Float16)d[j];     w2p[3][j] = (_Float16)d[2 + j];
        }
    }
    const float b2s = b2[0];
    const h2 zero2 = (h2)((_Float16)0.f);

    const long long ebase = ((long long)blockIdx.x * 4 + wid) * 16;

    short8 ub[4], vb[4];
#pragma unroll
    for (int g = 0; g < 4; ++g) {
        long long e = ebase + g * 4 + le;
        if (e >= E) e = E - 1;
        long long si, ti;
        if (i64f) {
            si = ((const long long*)src_raw)[e];
            ti = ((const long long*)tgt_raw)[e];
        } else {
            si = ((const int*)src_raw)[e];
            ti = ((const int*)tgt_raw)[e];
        }
        ub[g] = *reinterpret_cast<const short8*>(U + (unsigned)si * HID + lc * 8);
        vb[g] = *reinterpret_cast<const short8*>(V + (unsigned)ti * HID + lc * 8);
    }

#pragma unroll
    for (int g = 0; g < 4; ++g) {
        const unsigned int* uw = (const unsigned int*)&ub[g];
        const unsigned int* vw = (const unsigned int*)&vb[g];
        h2 s2 = zero2;
#pragma unroll
        for (int j = 0; j < 4; ++j) {
            h2 hu = __builtin_bit_cast(h2, uw[j]);
            h2 hv = __builtin_bit_cast(h2, vw[j]);
            h2 h  = hu + hv + b1p[j];
            h = __builtin_elementwise_max(h, zero2);
            s2 = s2 + h * w2p[j];
        }
        float s = (float)s2[0] + (float)s2[1];
#pragma unroll
        for (int w = 1; w < 16; w <<= 1)
            s += __shfl_xor(s, w, 16);
        const long long e = ebase + g * 4 + le;
        if (lc == 0 && e < E)
            out[e] = s + b2s;
    }
}

// ===========================================================================
// FALLBACK PATH (R3): MFMA over gathered rows (bf16), for tiny ws.
// ===========================================================================

__global__ void pack_w1_kernel(const float* __restrict__ W1, short* __restrict__ bpk) {
    int t = blockIdx.x * 256 + threadIdx.x;
    int f = (t >> 6) & 7;
    int l = t & 63;
    int n = t >> 9;
    int c = l & 15, kb = l >> 4;
    int k0 = f * 32 + kb * 8;
    short8 v;
#pragma unroll
    for (int j = 0; j < 8; ++j)
        v[j] = f2bf(W1[(k0 + j) * HID + n * 16 + c]);
    *reinterpret_cast<short8*>(&bpk[t * 8]) = v;
}

__global__ __launch_bounds__(256) void conv_emb_kernel(
    const float* __restrict__ emb, short* __restrict__ bemb, int n8) {
    int i = blockIdx.x * 256 + threadIdx.x;
    if (i >= n8) return;
    f32x4 x0 = *reinterpret_cast<const f32x4*>(emb + (size_t)i * 8);
    f32x4 x1 = *reinterpret_cast<const f32x4*>(emb + (size_t)i * 8 + 4);
    short8 v;
#pragma unroll
    for (int j = 0; j < 4; ++j) {
        v[j]     = f2bf(x0[j]);
        v[4 + j] = f2bf(x1[j]);
    }
    *reinterpret_cast<short8*>(&bemb[(size_t)i * 8]) = v;
}

template <int MODE>
__global__ __launch_bounds__(512, 4) void edge_head_kernel(
    const float* __restrict__ emb,
    const short* __restrict__ bemb,
    const void* __restrict__ src_raw,
    const void* __restrict__ tgt_raw,
    const float* __restrict__ W1,
    const float* __restrict__ b1,
    const float* __restrict__ W2,
    const float* __restrict__ b2,
    const short* __restrict__ bpk,
    float* __restrict__ out,
    int E)
{
    __shared__ short lds_b[32768];

    const int tid = threadIdx.x;

    int i64f = 1;
    {
        const int* s32 = (const int*)src_raw;
#pragma unroll
        for (int i = 1; i < 32; i += 2) i64f &= (s32[i] == 0);
    }

    if (MODE != 2) {
        const u32x4* g = (const u32x4*)bpk;
        u32x4* d = (u32x4*)lds_b;
#pragma unroll
        for (int i = 0; i < 8; ++i) d[i * 512 + tid] = g[i * 512 + tid];
    } else {
        for (int i = 0; i < 64; ++i) {
            int idx = i * 512 + tid;
            int col = idx & 127;
            int k   = idx >> 7;
            int n = col >> 4, cc = col & 15;
            int f = k >> 5, kb = (k >> 3) & 3, j = k & 7;
            int l2 = kb * 16 + cc;
            lds_b[(((n * 8 + f) * 64 + l2) << 3) + j] = f2bf(W1[idx]);
        }
    }
    __syncthreads();

    const int l = tid & 63;
    const int wid = tid >> 6;
    const int c = l & 15;
    const int g = l >> 4;
    const long long e0 = (long long)blockIdx.x * 256 + wid * 32;

    unsigned so[2], to[2];
#pragma unroll
    for (int m = 0; m < 2; ++m) {
        long long e = e0 + m * 16 + c;
        if (e >= E) e = E - 1;
        long long si, ti;
        if (i64f) {
            si = ((const long long*)src_raw)[e];
            ti = ((const long long*)tgt_raw)[e];
        } else {
            si = ((const int*)src_raw)[e];
            ti = ((const int*)tgt_raw)[e];
        }
        so[m] = (unsigned)si * HID;
        to[m] = (unsigned)ti * HID;
    }

    f32x4 acc[2][8];
#pragma unroll
    for (int m = 0; m < 2; ++m)
#pragma unroll
        for (int n = 0; n < 8; ++n)
            acc[m][n] = (f32x4){0.f, 0.f, 0.f, 0.f};

    const int koff = g * 8;
#pragma unroll
    for (int f = 0; f < 8; ++f) {
        short8 afr[2];
        const int k0 = (f & 3) * 32 + koff;
#pragma unroll
        for (int m = 0; m < 2; ++m) {
            const unsigned off = (f < 4 ? so[m] : to[m]) + k0;
            if (MODE == 0) {
                afr[m] = *reinterpret_cast<const short8*>(bemb + off);
            } else {
                f32x4 x0 = *reinterpret_cast<const f32x4*>(emb + off);
                f32x4 x1 = *reinterpret_cast<const f32x4*>(emb + off + 4);
                short8 t;
#pragma unroll
                for (int j = 0; j < 4; ++j) {
                    t[j]     = f2bf(x0[j]);
                    t[4 + j] = f2bf(x1[j]);
                }
                afr[m] = t;
            }
        }
#pragma unroll
        for (int n = 0; n < 8; ++n) {
            short8 bfr = *reinterpret_cast<const short8*>(&lds_b[((n * 8 + f) * 64 + l) * 8]);
#pragma unroll
            for (int m = 0; m < 2; ++m)
                acc[m][n] = __builtin_amdgcn_mfma_f32_16x16x32_bf16(afr[m], bfr, acc[m][n], 0, 0, 0);
        }
    }

    float b1v[8], w2v[8];
#pragma unroll
    for (int n = 0; n < 8; ++n) {
        b1v[n] = b1[n * 16 + c];
        w2v[n] = W2[n * 16 + c];
    }
    const float b2s = b2[0];

#pragma unroll
    for (int m = 0; m < 2; ++m) {
        float s[4] = {0.f, 0.f, 0.f, 0.f};
#pragma unroll
        for (int n = 0; n < 8; ++n) {
#pragma unroll
            for (int r = 0; r < 4; ++r)
                s[r] += fmaxf(acc[m][n][r] + b1v[n], 0.f) * w2v[n];
        }
#pragma unroll
        for (int w = 1; w < 16; w <<= 1) {
#pragma unroll
            for (int r = 0; r < 4; ++r)
                s[r] += __shfl_xor(s[r], w, 16);
        }
        if (c == 0) {
            const long long eb = e0 + m * 16 + g * 4;
#pragma unroll
            for (int r = 0; r < 4; ++r)
                if (eb + r < E) out[eb + r] = s[r] + b2s;
        }
    }
}

extern "C" void kernel_launch(void* const* d_in, const int* in_sizes, int n_in,
                              void* d_out, int out_size, void* d_ws, size_t ws_size,
                              hipStream_t stream) {
    const float* emb = (const float*)d_in[0];
    const void*  src = d_in[1];
    const void*  tgt = d_in[2];
    // d_in[3] = edge_type_idx (selector; params passed are already the selected ones)
    const float* W1 = (const float*)d_in[4];
    const float* b1 = (const float*)d_in[5];
    const float* W2 = (const float*)d_in[6];
    const float* b2 = (const float*)d_in[7];
    float* out = (float*)d_out;

    const int E  = in_sizes[1];
    const int Nn = in_sizes[0] / HID;

    const size_t uv_bytes  = (size_t)Nn * HID * sizeof(short);
    // sorted-path layout: bpk2 64K | gh 16K | cursor 16K | U | V | ss | tt | ei
    const size_t off_gh   = 65536;
    const size_t off_cur  = off_gh + NBUK * 4;
    const size_t off_U    = off_cur + NBUK * 4;
    const size_t off_V    = off_U + uv_bytes;
    const size_t off_ss   = off_V + uv_bytes;
    const size_t off_tt   = off_ss + (size_t)E * 4;
    const size_t off_ei   = off_tt + (size_t)E * 4;
    const size_t need_sort = off_ei + (size_t)E * 4;
    const size_t need_uv   = 65536 + 2 * uv_bytes;
    const size_t need_old  = 65536 + (size_t)in_sizes[0] * sizeof(short);

    if (ws_size >= need_sort) {
        short*          bpk2   = (short*)d_ws;
        int*            gh     = (int*)((char*)d_ws + off_gh);
        int*            cursor = (int*)((char*)d_ws + off_cur);
        unsigned short* U      = (unsigned short*)((char*)d_ws + off_U);
        unsigned short* Vv     = (unsigned short*)((char*)d_ws + off_V);
        int*            ss     = (int*)((char*)d_ws + off_ss);
        int*            tt     = (int*)((char*)d_ws + off_tt);
        int*            ei     = (int*)((char*)d_ws + off_ei);

        int shift = 0;
        while (((long long)(Nn - 1) >> shift) >= NBUK) ++shift;
        if (shift < 5) shift = 5;   // >=32 nodes (8KB U-slice) per bucket

        zero_hist_kernel<<<16, 256, 0, stream>>>(gh);
        pack_w1_uv_kernel<<<16, 256, 0, stream>>>(W1, bpk2);
        hist_kernel<<<256, 256, 0, stream>>>(src, E, shift, gh);
        uv_kernel<<<(Nn + 127) / 128, 512, 0, stream>>>(emb, bpk2, U, Vv, Nn);
        scan_kernel<<<1, 1024, 0, stream>>>(gh, cursor);
        scatter_kernel<<<512, 256, 0, stream>>>(src, tgt, E, shift, cursor, ss, tt, ei);
        edge_pass_sorted_kernel<<<(E + 63) / 64, 256, 0, stream>>>(
            U, Vv, ss, tt, ei, b1, W2, b2, out, E);
        return;
    }

    if (ws_size >= need_uv) {
        short*          bpk2 = (short*)d_ws;
        unsigned short* U    = (unsigned short*)((char*)d_ws + 65536);
        unsigned short* Vv   = (unsigned short*)((char*)d_ws + 65536 + uv_bytes);

        pack_w1_uv_kernel<<<16, 256, 0, stream>>>(W1, bpk2);
        uv_kernel<<<(Nn + 127) / 128, 512, 0, stream>>>(emb, bpk2, U, Vv, Nn);
        edge_pass_kernel<<<(E + 63) / 64, 256, 0, stream>>>(U, Vv, src, tgt, b1, W2, b2, out, E);
        return;
    }

    // ---- fallback: R3 gathered-MFMA path
    short* bpk  = (short*)d_ws;
    short* bemb = (short*)((char*)d_ws + 65536);

    int mode;
    if (ws_size >= need_old)        mode = 0;
    else if (ws_size >= 65536)      mode = 1;
    else                            mode = 2;

    if (mode != 2)
        pack_w1_kernel<<<16, 256, 0, stream>>>(W1, bpk);
    if (mode == 0) {
        const int n8 = in_sizes[0] / 8;
        conv_emb_kernel<<<(n8 + 255) / 256, 256, 0, stream>>>(emb, bemb, n8);
    }

    const int grid = (E + 255) / 256;
    if (mode == 0)
        edge_head_kernel<0><<<grid, 512, 0, stream>>>(emb, bemb, src, tgt, W1, b1, W2, b2, bpk, out, E);
    else if (mode == 1)
        edge_head_kernel<1><<<grid, 512, 0, stream>>>(emb, bemb, src, tgt, W1, b1, W2, b2, bpk, out, E);
    else
        edge_head_kernel<2><<<grid, 512, 0, stream>>>(emb, bemb, src, tgt, W1, b1, W2, b2, bpk, out, E);
}

// Round 14
// 150.712 us; speedup vs baseline: 1.8022x; 1.8022x over previous
//
#include <hip/hip_runtime.h>
#include <hip/hip_bf16.h>

#define HID 128

typedef __attribute__((ext_vector_type(8))) short short8;
typedef __attribute__((ext_vector_type(4))) float f32x4;
typedef __attribute__((ext_vector_type(16))) float f32x16;
typedef __attribute__((ext_vector_type(4))) unsigned int u32x4;
typedef __attribute__((ext_vector_type(2))) _Float16 h2;

__device__ __forceinline__ short f2bf(float x) {
    __bf16 b = (__bf16)x;
    return __builtin_bit_cast(short, b);
}

// ===========================================================================
// FACTORED PATH: U = emb@W1[:128], V = emb@W1[128:] (dense per-node GEMM),
// then out[e] = relu(U[src]+V[tgt]+b1)@W2 + b2 (gather + packed-fp16 VALU).
// R14: coarse 64-bucket tgt-partition (cheap LDS-staged scatter) + XCD-
// affine edge pass: XCD p owns buckets [8p,8p+8) -> its V-slice (~3.2MB)
// is L2-resident; active sub-bucket slice ~0.5MB -> short reuse distance.
// ===========================================================================

// ---------------------------------------------------------------------------
// Pack W1 halves into 32x32x16 MFMA-B fragment order (bf16), both halves.
// ---------------------------------------------------------------------------
__global__ void pack_w1_uv_kernel(const float* __restrict__ W1, short* __restrict__ bpk2) {
    int t = blockIdx.x * 256 + threadIdx.x;   // 0..4095 = half*2048 + nt*512 + ks*64 + l
    int l    = t & 63;
    int ks   = (t >> 6) & 7;
    int nt   = (t >> 9) & 3;
    int half = t >> 11;
    int k0  = half * 128 + ks * 16 + (l >> 5) * 8;
    int col = nt * 32 + (l & 31);
    short8 v;
#pragma unroll
    for (int j = 0; j < 8; ++j)
        v[j] = f2bf(W1[(k0 + j) * HID + col]);
    *reinterpret_cast<short8*>(&bpk2[t * 8]) = v;
}

// ---------------------------------------------------------------------------
// UV precompute (fp16 output): mfma_f32_32x32x16_bf16, 128 nodes/block.
// ---------------------------------------------------------------------------
__global__ __launch_bounds__(512, 4) void uv_kernel(
    const float* __restrict__ emb,
    const short* __restrict__ bpk2,
    unsigned short* __restrict__ U,
    unsigned short* __restrict__ V,
    int Nn)
{
    __shared__ short lds_b[32768];

    const int tid = threadIdx.x;
    const int l   = tid & 63;
    const int wid = tid >> 6;
    const int wg  = wid >> 1;
    const int wn  = wid & 1;
    const int lc  = l & 31;
    const int hi  = l >> 5;

    {
        const u32x4* g = (const u32x4*)bpk2;
        u32x4* d = (u32x4*)lds_b;
#pragma unroll
        for (int i = 0; i < 8; ++i) d[i * 512 + tid] = g[i * 512 + tid];
    }
    __syncthreads();

    const int base = blockIdx.x * 128 + wg * 32;
    int nr = base + lc;
    if (nr >= Nn) nr = Nn - 1;

    f32x16 accU[2], accV[2];
#pragma unroll
    for (int n = 0; n < 2; ++n) { accU[n] = (f32x16)(0.f); accV[n] = (f32x16)(0.f); }

#pragma unroll
    for (int ks = 0; ks < 8; ++ks) {
        const float* p = emb + (size_t)nr * HID + ks * 16 + hi * 8;
        f32x4 x0 = *reinterpret_cast<const f32x4*>(p);
        f32x4 x1 = *reinterpret_cast<const f32x4*>(p + 4);
        short8 afr;
#pragma unroll
        for (int j = 0; j < 4; ++j) { afr[j] = f2bf(x0[j]); afr[4 + j] = f2bf(x1[j]); }
#pragma unroll
        for (int n = 0; n < 2; ++n) {
            const int nt = wn * 2 + n;
            short8 bU = *reinterpret_cast<const short8*>(&lds_b[(((0 + nt) * 8 + ks) * 64 + l) * 8]);
            short8 bV = *reinterpret_cast<const short8*>(&lds_b[(((4 + nt) * 8 + ks) * 64 + l) * 8]);
            accU[n] = __builtin_amdgcn_mfma_f32_32x32x16_bf16(afr, bU, accU[n], 0, 0, 0);
            accV[n] = __builtin_amdgcn_mfma_f32_32x32x16_bf16(afr, bV, accV[n], 0, 0, 0);
        }
    }

#pragma unroll
    for (int n = 0; n < 2; ++n) {
        const int col = wn * 64 + n * 32 + lc;
#pragma unroll
        for (int r = 0; r < 16; ++r) {
            const int row = (r & 3) + 8 * (r >> 2) + 4 * hi;
            const int node = base + row;
            if (node < Nn) {
                _Float16 hu = (_Float16)accU[n][r];
                _Float16 hv = (_Float16)accV[n][r];
                U[(size_t)node * HID + col] = __builtin_bit_cast(unsigned short, hu);
                V[(size_t)node * HID + col] = __builtin_bit_cast(unsigned short, hv);
            }
        }
    }
}

// ---------------------------------------------------------------------------
// 64-bucket histogram over tgt. bucket = min(63, (int)(t * bscale)),
// bscale = 64/Nn (monotone, balanced for uniform tgt). Identical expression
// in hist and scatter -> identical bucketing.
// ---------------------------------------------------------------------------
__global__ __launch_bounds__(256) void hist64_kernel(
    const void* __restrict__ src_raw, const void* __restrict__ tgt_raw,
    int E, float bscale, int* __restrict__ gh)
{
    __shared__ int lh[64];
    const int tid = threadIdx.x;
    if (tid < 64) lh[tid] = 0;
    __syncthreads();

    int i64f = 1;
    {
        const int* s32 = (const int*)src_raw;
#pragma unroll
        for (int i = 1; i < 32; i += 2) i64f &= (s32[i] == 0);
    }
    const int stride = gridDim.x * 256;
    for (int e = blockIdx.x * 256 + tid; e < E; e += stride) {
        int t = i64f ? (int)((const long long*)tgt_raw)[e]
                     : ((const int*)tgt_raw)[e];
        int b = (int)((float)t * bscale);
        b = b < 0 ? 0 : (b > 63 ? 63 : b);
        atomicAdd(&lh[b], 1);
    }
    __syncthreads();
    if (tid < 64 && lh[tid]) atomicAdd(&gh[tid], lh[tid]);
}

// ---------------------------------------------------------------------------
// Bucket offsets: goff[64] (exclusive prefix) and off8[9] (per-XCD ranges).
// ---------------------------------------------------------------------------
__global__ void off64_kernel(const int* __restrict__ gh,
                             int* __restrict__ goff, int* __restrict__ off8) {
    __shared__ int h[64];
    const int t = threadIdx.x;
    h[t] = gh[t];
    __syncthreads();
    if (t == 0) {
        int acc = 0;
        for (int b = 0; b < 64; ++b) {
            goff[b] = acc;
            if ((b & 7) == 0) off8[b >> 3] = acc;
            acc += h[b];
        }
        off8[8] = acc;
    }
}

// ---------------------------------------------------------------------------
// LDS-staged partition scatter: 2048 edges/block; per-block bucket counts,
// 64 per-block cursor atomics, LDS placement, semi-coalesced run writes.
// ---------------------------------------------------------------------------
__global__ __launch_bounds__(256) void scatter64_kernel(
    const void* __restrict__ src_raw, const void* __restrict__ tgt_raw,
    int E, float bscale,
    const int* __restrict__ goff, int* __restrict__ cursor,
    int* __restrict__ ss, int* __restrict__ tt, int* __restrict__ ei)
{
    __shared__ int lh[64], lh2[64], lo[64], grb[64], go[64];
    __shared__ int sS[2048], sT[2048], sE[2048], bk[2048];

    const int tid = threadIdx.x;
    int i64f = 1;
    {
        const int* s32 = (const int*)src_raw;
#pragma unroll
        for (int i = 1; i < 32; i += 2) i64f &= (s32[i] == 0);
    }
    if (tid < 64) { lh[tid] = 0; lh2[tid] = 0; go[tid] = goff[tid]; }
    __syncthreads();

    const int base = blockIdx.x * 2048;
    int myS[8], myT[8], myB[8];
#pragma unroll
    for (int k = 0; k < 8; ++k) {
        const int e = base + k * 256 + tid;
        myB[k] = -1;
        if (e < E) {
            int s, t;
            if (i64f) {
                s = (int)((const long long*)src_raw)[e];
                t = (int)((const long long*)tgt_raw)[e];
            } else {
                s = ((const int*)src_raw)[e];
                t = ((const int*)tgt_raw)[e];
            }
            int b = (int)((float)t * bscale);
            b = b < 0 ? 0 : (b > 63 ? 63 : b);
            myS[k] = s; myT[k] = t; myB[k] = b;
            atomicAdd(&lh[b], 1);
        }
    }
    __syncthreads();
    if (tid == 0) {
        int acc = 0;
        for (int b = 0; b < 64; ++b) { lo[b] = acc; acc += lh[b]; }
    }
    __syncthreads();
    if (tid < 64 && lh[tid] > 0) grb[tid] = atomicAdd(&cursor[tid], lh[tid]);
    __syncthreads();
#pragma unroll
    for (int k = 0; k < 8; ++k) {
        if (myB[k] >= 0) {
            const int b = myB[k];
            const int pl = lo[b] + atomicAdd(&lh2[b], 1);
            sS[pl] = myS[k];
            sT[pl] = myT[k];
            sE[pl] = base + k * 256 + tid;
            bk[pl] = b;
        }
    }
    __syncthreads();
    const int total = lo[63] + lh[63];
    for (int i = tid; i < total; i += 256) {
        const int b = bk[i];
        const int dst = go[b] + grb[b] + (i - lo[b]);
        ss[dst] = sS[i];
        tt[dst] = sT[i];
        ei[dst] = sE[i];
    }
}

// ---------------------------------------------------------------------------
// Partitioned edge pass: XCD p (blockIdx%8, round-robin dispatch) processes
// edges [off8[p], off8[p+1]) via grid-stride -> its V-slice stays in its L2.
// fp16 packed math as R12.
// ---------------------------------------------------------------------------
__global__ __launch_bounds__(256) void edge_pass_part_kernel(
    const unsigned short* __restrict__ U,
    const unsigned short* __restrict__ V,
    const int* __restrict__ ss,
    const int* __restrict__ tt,
    const int* __restrict__ ei,
    const int* __restrict__ off8,
    const float* __restrict__ b1,
    const float* __restrict__ W2,
    const float* __restrict__ b2,
    float* __restrict__ out,
    int per_x)
{
    const int tid = threadIdx.x;
    const int l   = tid & 63;
    const int wid = tid >> 6;
    const int le  = l >> 4;          // edge slot in group (0..3)
    const int lc  = l & 15;          // col group: cols [lc*8, lc*8+8)
    const int p   = blockIdx.x & 7;  // XCD (round-robin dispatch assumption)
    const int r   = blockIdx.x >> 3;

    const int pbeg = off8[p];
    const int pend = off8[p + 1];

    h2 b1p[4], w2p[4];
    {
        f32x4 a = *reinterpret_cast<const f32x4*>(b1 + lc * 8);
        f32x4 b = *reinterpret_cast<const f32x4*>(b1 + lc * 8 + 4);
        f32x4 c = *reinterpret_cast<const f32x4*>(W2 + lc * 8);
        f32x4 d = *reinterpret_cast<const f32x4*>(W2 + lc * 8 + 4);
#pragma unroll
        for (int j = 0; j < 2; ++j) {
            b1p[0][j] = (_Float16)a[j];     b1p[1][j] = (_Float16)a[2 + j];
            b1p[2][j] = (_Float16)b[j];     b1p[3][j] = (_Float16)b[2 + j];
            w2p[0][j] = (_Float16)c[j];     w2p[1][j] = (_Float16)c[2 + j];
            w2p[2][j] = (_Float16)d[j];     w2p[3][j] = (_Float16)d[2 + j];
        }
    }
    const float b2s = b2[0];
    const h2 zero2 = (h2)((_Float16)0.f);

    for (int base = pbeg + r * 64; base < pend; base += per_x * 64) {
        short8 ub[4], vb[4];
        int oid[4];
        bool live[4];
#pragma unroll
        for (int g = 0; g < 4; ++g) {
            int pos = base + wid * 16 + g * 4 + le;
            live[g] = (pos < pend);
            if (!live[g]) pos = base;
            const int s = ss[pos];
            const int t = tt[pos];
            oid[g] = ei[pos];
            ub[g] = *reinterpret_cast<const short8*>(U + (unsigned)s * HID + lc * 8);
            vb[g] = *reinterpret_cast<const short8*>(V + (unsigned)t * HID + lc * 8);
        }

#pragma unroll
        for (int g = 0; g < 4; ++g) {
            const unsigned int* uw = (const unsigned int*)&ub[g];
            const unsigned int* vw = (const unsigned int*)&vb[g];
            h2 s2 = zero2;
#pragma unroll
            for (int j = 0; j < 4; ++j) {
                h2 hu = __builtin_bit_cast(h2, uw[j]);
                h2 hv = __builtin_bit_cast(h2, vw[j]);
                h2 h  = hu + hv + b1p[j];
                h = __builtin_elementwise_max(h, zero2);
                s2 = s2 + h * w2p[j];
            }
            float s = (float)s2[0] + (float)s2[1];
#pragma unroll
            for (int w = 1; w < 16; w <<= 1)
                s += __shfl_xor(s, w, 16);
            if (lc == 0 && live[g])
                out[oid[g]] = s + b2s;
        }
    }
}

// ---------------------------------------------------------------------------
// Unsorted edge pass (R12 path, fallback when ws can't hold partition arrays).
// ---------------------------------------------------------------------------
__global__ __launch_bounds__(256) void edge_pass_kernel(
    const unsigned short* __restrict__ U,
    const unsigned short* __restrict__ V,
    const void* __restrict__ src_raw,
    const void* __restrict__ tgt_raw,
    const float* __restrict__ b1,
    const float* __restrict__ W2,
    const float* __restrict__ b2,
    float* __restrict__ out,
    int E)
{
    const int tid = threadIdx.x;
    const int l   = tid & 63;
    const int wid = tid >> 6;
    const int le  = l >> 4;
    const int lc  = l & 15;

    int oddw = 0;
    {
        const int* s32 = (const int*)src_raw;
        if (l < 32) oddw = s32[2 * l + 1];
    }
    const bool i64f = (__ballot(oddw != 0) == 0ULL);

    h2 b1p[4], w2p[4];
    {
        f32x4 a = *reinterpret_cast<const f32x4*>(b1 + lc * 8);
        f32x4 b = *reinterpret_cast<const f32x4*>(b1 + lc * 8 + 4);
        f32x4 c = *reinterpret_cast<const f32x4*>(W2 + lc * 8);
        f32x4 d = *reinterpret_cast<const f32x4*>(W2 + lc * 8 + 4);
#pragma unroll
        for (int j = 0; j < 2; ++j) {
            b1p[0][j] = (_Float16)a[j];     b1p[1][j] = (_Float16)a[2 + j];
            b1p[2][j] = (_Float16)b[j];     b1p[3][j] = (_Float16)b[2 + j];
            w2p[0][j] = (_Float16)c[j];     w2p[1][j] = (_Float16)c[2 + j];
            w2p[2][j] = (_Float16)d[j];     w2p[3][j] = (_Float16)d[2 + j];
        }
    }
    const float b2s = b2[0];
    const h2 zero2 = (h2)((_Float16)0.f);

    const long long ebase = ((long long)blockIdx.x * 4 + wid) * 16;

    short8 ub[4], vb[4];
#pragma unroll
    for (int g = 0; g < 4; ++g) {
        long long e = ebase + g * 4 + le;
        if (e >= E) e = E - 1;
        long long si, ti;
        if (i64f) {
            si = ((const long long*)src_raw)[e];
            ti = ((const long long*)tgt_raw)[e];
        } else {
            si = ((const int*)src_raw)[e];
            ti = ((const int*)tgt_raw)[e];
        }
        ub[g] = *reinterpret_cast<const short8*>(U + (unsigned)si * HID + lc * 8);
        vb[g] = *reinterpret_cast<const short8*>(V + (unsigned)ti * HID + lc * 8);
    }

#pragma unroll
    for (int g = 0; g < 4; ++g) {
        const unsigned int* uw = (const unsigned int*)&ub[g];
        const unsigned int* vw = (const unsigned int*)&vb[g];
        h2 s2 = zero2;
#pragma unroll
        for (int j = 0; j < 4; ++j) {
            h2 hu = __builtin_bit_cast(h2, uw[j]);
            h2 hv = __builtin_bit_cast(h2, vw[j]);
            h2 h  = hu + hv + b1p[j];
            h = __builtin_elementwise_max(h, zero2);
            s2 = s2 + h * w2p[j];
        }
        float s = (float)s2[0] + (float)s2[1];
#pragma unroll
        for (int w = 1; w < 16; w <<= 1)
            s += __shfl_xor(s, w, 16);
        const long long e = ebase + g * 4 + le;
        if (lc == 0 && e < E)
            out[e] = s + b2s;
    }
}

// ===========================================================================
// FALLBACK PATH (R3): MFMA over gathered rows (bf16), for tiny ws.
// ===========================================================================

__global__ void pack_w1_kernel(const float* __restrict__ W1, short* __restrict__ bpk) {
    int t = blockIdx.x * 256 + threadIdx.x;
    int f = (t >> 6) & 7;
    int l = t & 63;
    int n = t >> 9;
    int c = l & 15, kb = l >> 4;
    int k0 = f * 32 + kb * 8;
    short8 v;
#pragma unroll
    for (int j = 0; j < 8; ++j)
        v[j] = f2bf(W1[(k0 + j) * HID + n * 16 + c]);
    *reinterpret_cast<short8*>(&bpk[t * 8]) = v;
}

__global__ __launch_bounds__(256) void conv_emb_kernel(
    const float* __restrict__ emb, short* __restrict__ bemb, int n8) {
    int i = blockIdx.x * 256 + threadIdx.x;
    if (i >= n8) return;
    f32x4 x0 = *reinterpret_cast<const f32x4*>(emb + (size_t)i * 8);
    f32x4 x1 = *reinterpret_cast<const f32x4*>(emb + (size_t)i * 8 + 4);
    short8 v;
#pragma unroll
    for (int j = 0; j < 4; ++j) {
        v[j]     = f2bf(x0[j]);
        v[4 + j] = f2bf(x1[j]);
    }
    *reinterpret_cast<short8*>(&bemb[(size_t)i * 8]) = v;
}

template <int MODE>
__global__ __launch_bounds__(512, 4) void edge_head_kernel(
    const float* __restrict__ emb,
    const short* __restrict__ bemb,
    const void* __restrict__ src_raw,
    const void* __restrict__ tgt_raw,
    const float* __restrict__ W1,
    const float* __restrict__ b1,
    const float* __restrict__ W2,
    const float* __restrict__ b2,
    const short* __restrict__ bpk,
    float* __restrict__ out,
    int E)
{
    __shared__ short lds_b[32768];

    const int tid = threadIdx.x;

    int i64f = 1;
    {
        const int* s32 = (const int*)src_raw;
#pragma unroll
        for (int i = 1; i < 32; i += 2) i64f &= (s32[i] == 0);
    }

    if (MODE != 2) {
        const u32x4* g = (const u32x4*)bpk;
        u32x4* d = (u32x4*)lds_b;
#pragma unroll
        for (int i = 0; i < 8; ++i) d[i * 512 + tid] = g[i * 512 + tid];
    } else {
        for (int i = 0; i < 64; ++i) {
            int idx = i * 512 + tid;
            int col = idx & 127;
            int k   = idx >> 7;
            int n = col >> 4, cc = col & 15;
            int f = k >> 5, kb = (k >> 3) & 3, j = k & 7;
            int l2 = kb * 16 + cc;
            lds_b[(((n * 8 + f) * 64 + l2) << 3) + j] = f2bf(W1[idx]);
        }
    }
    __syncthreads();

    const int l = tid & 63;
    const int wid = tid >> 6;
    const int c = l & 15;
    const int g = l >> 4;
    const long long e0 = (long long)blockIdx.x * 256 + wid * 32;

    unsigned so[2], to[2];
#pragma unroll
    for (int m = 0; m < 2; ++m) {
        long long e = e0 + m * 16 + c;
        if (e >= E) e = E - 1;
        long long si, ti;
        if (i64f) {
            si = ((const long long*)src_raw)[e];
            ti = ((const long long*)tgt_raw)[e];
        } else {
            si = ((const int*)src_raw)[e];
            ti = ((const int*)tgt_raw)[e];
        }
        so[m] = (unsigned)si * HID;
        to[m] = (unsigned)ti * HID;
    }

    f32x4 acc[2][8];
#pragma unroll
    for (int m = 0; m < 2; ++m)
#pragma unroll
        for (int n = 0; n < 8; ++n)
            acc[m][n] = (f32x4){0.f, 0.f, 0.f, 0.f};

    const int koff = g * 8;
#pragma unroll
    for (int f = 0; f < 8; ++f) {
        short8 afr[2];
        const int k0 = (f & 3) * 32 + koff;
#pragma unroll
        for (int m = 0; m < 2; ++m) {
            const unsigned off = (f < 4 ? so[m] : to[m]) + k0;
            if (MODE == 0) {
                afr[m] = *reinterpret_cast<const short8*>(bemb + off);
            } else {
                f32x4 x0 = *reinterpret_cast<const f32x4*>(emb + off);
                f32x4 x1 = *reinterpret_cast<const f32x4*>(emb + off + 4);
                short8 t;
#pragma unroll
                for (int j = 0; j < 4; ++j) {
                    t[j]     = f2bf(x0[j]);
                    t[4 + j] = f2bf(x1[j]);
                }
                afr[m] = t;
            }
        }
#pragma unroll
        for (int n = 0; n < 8; ++n) {
            short8 bfr = *reinterpret_cast<const short8*>(&lds_b[((n * 8 + f) * 64 + l) * 8]);
#pragma unroll
            for (int m = 0; m < 2; ++m)
                acc[m][n] = __builtin_amdgcn_mfma_f32_16x16x32_bf16(afr[m], bfr, acc[m][n], 0, 0, 0);
        }
    }

    float b1v[8], w2v[8];
#pragma unroll
    for (int n = 0; n < 8; ++n) {
        b1v[n] = b1[n * 16 + c];
        w2v[n] = W2[n * 16 + c];
    }
    const float b2s = b2[0];

#pragma unroll
    for (int m = 0; m < 2; ++m) {
        float s[4] = {0.f, 0.f, 0.f, 0.f};
#pragma unroll
        for (int n = 0; n < 8; ++n) {
#pragma unroll
            for (int r = 0; r < 4; ++r)
                s[r] += fmaxf(acc[m][n][r] + b1v[n], 0.f) * w2v[n];
        }
#pragma unroll
        for (int w = 1; w < 16; w <<= 1) {
#pragma unroll
            for (int r = 0; r < 4; ++r)
                s[r] += __shfl_xor(s[r], w, 16);
        }
        if (c == 0) {
            const long long eb = e0 + m * 16 + g * 4;
#pragma unroll
            for (int r = 0; r < 4; ++r)
                if (eb + r < E) out[eb + r] = s[r] + b2s;
        }
    }
}

extern "C" void kernel_launch(void* const* d_in, const int* in_sizes, int n_in,
                              void* d_out, int out_size, void* d_ws, size_t ws_size,
                              hipStream_t stream) {
    const float* emb = (const float*)d_in[0];
    const void*  src = d_in[1];
    const void*  tgt = d_in[2];
    // d_in[3] = edge_type_idx (selector; params passed are already the selected ones)
    const float* W1 = (const float*)d_in[4];
    const float* b1 = (const float*)d_in[5];
    const float* W2 = (const float*)d_in[6];
    const float* b2 = (const float*)d_in[7];
    float* out = (float*)d_out;

    const int E  = in_sizes[1];
    const int Nn = in_sizes[0] / HID;

    const size_t uv_bytes = (size_t)Nn * HID * sizeof(short);
    // partitioned layout: bpk2 64K | gh 256 | cursor 256 | goff 256 | off8 256
    //                     | pad to 64K+4K | U | V | ss | tt | ei
    const size_t off_gh   = 65536;
    const size_t off_cur  = off_gh + 256;
    const size_t off_goff = off_cur + 256;
    const size_t off_off8 = off_goff + 256;
    const size_t off_U    = 65536 + 4096;
    const size_t off_V    = off_U + uv_bytes;
    const size_t off_ss   = off_V + uv_bytes;
    const size_t off_tt   = off_ss + (size_t)E * 4;
    const size_t off_ei   = off_tt + (size_t)E * 4;
    const size_t need_part = off_ei + (size_t)E * 4;
    const size_t need_uv   = 65536 + 2 * uv_bytes;
    const size_t need_old  = 65536 + (size_t)in_sizes[0] * sizeof(short);

    if (ws_size >= need_part && E >= 4096) {
        short*          bpk2   = (short*)d_ws;
        int*            gh     = (int*)((char*)d_ws + off_gh);
        int*            cursor = (int*)((char*)d_ws + off_cur);
        int*            goff   = (int*)((char*)d_ws + off_goff);
        int*            off8   = (int*)((char*)d_ws + off_off8);
        unsigned short* U      = (unsigned short*)((char*)d_ws + off_U);
        unsigned short* Vv     = (unsigned short*)((char*)d_ws + off_V);
        int*            ss     = (int*)((char*)d_ws + off_ss);
        int*            tt     = (int*)((char*)d_ws + off_tt);
        int*            ei     = (int*)((char*)d_ws + off_ei);

        const float bscale = 63.9999f / (float)Nn;

        hipMemsetAsync((char*)d_ws + off_gh, 0, 512, stream);   // gh + cursor
        pack_w1_uv_kernel<<<16, 256, 0, stream>>>(W1, bpk2);
        hist64_kernel<<<256, 256, 0, stream>>>(src, tgt, E, bscale, gh);
        uv_kernel<<<(Nn + 127) / 128, 512, 0, stream>>>(emb, bpk2, U, Vv, Nn);
        off64_kernel<<<1, 64, 0, stream>>>(gh, goff, off8);
        scatter64_kernel<<<(E + 2047) / 2048, 256, 0, stream>>>(
            src, tgt, E, bscale, goff, cursor, ss, tt, ei);
        const int per_x = (E / 8 + 4096) / 64 + 2;
        edge_pass_part_kernel<<<per_x * 8, 256, 0, stream>>>(
            U, Vv, ss, tt, ei, off8, b1, W2, b2, out, per_x);
        return;
    }

    if (ws_size >= need_uv) {
        short*          bpk2 = (short*)d_ws;
        unsigned short* U    = (unsigned short*)((char*)d_ws + 65536);
        unsigned short* Vv   = (unsigned short*)((char*)d_ws + 65536 + uv_bytes);

        pack_w1_uv_kernel<<<16, 256, 0, stream>>>(W1, bpk2);
        uv_kernel<<<(Nn + 127) / 128, 512, 0, stream>>>(emb, bpk2, U, Vv, Nn);
        edge_pass_kernel<<<(E + 63) / 64, 256, 0, stream>>>(U, Vv, src, tgt, b1, W2, b2, out, E);
        return;
    }

    // ---- fallback: R3 gathered-MFMA path
    short* bpk  = (short*)d_ws;
    short* bemb = (short*)((char*)d_ws + 65536);

    int mode;
    if (ws_size >= need_old)        mode = 0;
    else if (ws_size >= 65536)      mode = 1;
    else                            mode = 2;

    if (mode != 2)
        pack_w1_kernel<<<16, 256, 0, stream>>>(W1, bpk);
    if (mode == 0) {
        const int n8 = in_sizes[0] / 8;
        conv_emb_kernel<<<(n8 + 255) / 256, 256, 0, stream>>>(emb, bemb, n8);
    }

    const int grid = (E + 255) / 256;
    if (mode == 0)
        edge_head_kernel<0><<<grid, 512, 0, stream>>>(emb, bemb, src, tgt, W1, b1, W2, b2, bpk, out, E);
    else if (mode == 1)
        edge_head_kernel<1><<<grid, 512, 0, stream>>>(emb, bemb, src, tgt, W1, b1, W2, b2, bpk, out, E);
    else
        edge_head_kernel<2><<<grid, 512, 0, stream>>>(emb, bemb, src, tgt, W1, b1, W2, b2, bpk, out, E);
}

// Round 15
// 149.713 us; speedup vs baseline: 1.8143x; 1.0067x over previous
//
#include <hip/hip_runtime.h>
#include <hip/hip_bf16.h>

#define HID 128

typedef __attribute__((ext_vector_type(8))) short short8;
typedef __attribute__((ext_vector_type(4))) float f32x4;
typedef __attribute__((ext_vector_type(16))) float f32x16;
typedef __attribute__((ext_vector_type(4))) unsigned int u32x4;
typedef __attribute__((ext_vector_type(2))) _Float16 h2;

__device__ __forceinline__ short f2bf(float x) {
    __bf16 b = (__bf16)x;
    return __builtin_bit_cast(short, b);
}

// ===========================================================================
// FACTORED PATH: U = emb@W1[:128], V = emb@W1[128:] (dense per-node GEMM),
// then out[e] = relu(U[src]+V[tgt]+b1)@W2 + b2 (gather + packed-fp16 VALU).
// R14: coarse 64-bucket tgt-partition (cheap LDS-staged scatter) + XCD-
// affine edge pass: XCD p owns buckets [8p,8p+8) -> its V-slice (~3.2MB)
// is L2-resident; active sub-bucket slice ~0.5MB -> short reuse distance.
// ===========================================================================

// ---------------------------------------------------------------------------
// Pack W1 halves into 32x32x16 MFMA-B fragment order (bf16), both halves.
// ---------------------------------------------------------------------------
__global__ void pack_w1_uv_kernel(const float* __restrict__ W1, short* __restrict__ bpk2) {
    int t = blockIdx.x * 256 + threadIdx.x;   // 0..4095 = half*2048 + nt*512 + ks*64 + l
    int l    = t & 63;
    int ks   = (t >> 6) & 7;
    int nt   = (t >> 9) & 3;
    int half = t >> 11;
    int k0  = half * 128 + ks * 16 + (l >> 5) * 8;
    int col = nt * 32 + (l & 31);
    short8 v;
#pragma unroll
    for (int j = 0; j < 8; ++j)
        v[j] = f2bf(W1[(k0 + j) * HID + col]);
    *reinterpret_cast<short8*>(&bpk2[t * 8]) = v;
}

// ---------------------------------------------------------------------------
// UV precompute (fp16 output): mfma_f32_32x32x16_bf16, 128 nodes/block.
// ---------------------------------------------------------------------------
__global__ __launch_bounds__(512, 4) void uv_kernel(
    const float* __restrict__ emb,
    const short* __restrict__ bpk2,
    unsigned short* __restrict__ U,
    unsigned short* __restrict__ V,
    int Nn)
{
    __shared__ short lds_b[32768];

    const int tid = threadIdx.x;
    const int l   = tid & 63;
    const int wid = tid >> 6;
    const int wg  = wid >> 1;
    const int wn  = wid & 1;
    const int lc  = l & 31;
    const int hi  = l >> 5;

    {
        const u32x4* g = (const u32x4*)bpk2;
        u32x4* d = (u32x4*)lds_b;
#pragma unroll
        for (int i = 0; i < 8; ++i) d[i * 512 + tid] = g[i * 512 + tid];
    }
    __syncthreads();

    const int base = blockIdx.x * 128 + wg * 32;
    int nr = base + lc;
    if (nr >= Nn) nr = Nn - 1;

    f32x16 accU[2], accV[2];
#pragma unroll
    for (int n = 0; n < 2; ++n) { accU[n] = (f32x16)(0.f); accV[n] = (f32x16)(0.f); }

#pragma unroll
    for (int ks = 0; ks < 8; ++ks) {
        const float* p = emb + (size_t)nr * HID + ks * 16 + hi * 8;
        f32x4 x0 = *reinterpret_cast<const f32x4*>(p);
        f32x4 x1 = *reinterpret_cast<const f32x4*>(p + 4);
        short8 afr;
#pragma unroll
        for (int j = 0; j < 4; ++j) { afr[j] = f2bf(x0[j]); afr[4 + j] = f2bf(x1[j]); }
#pragma unroll
        for (int n = 0; n < 2; ++n) {
            const int nt = wn * 2 + n;
            short8 bU = *reinterpret_cast<const short8*>(&lds_b[(((0 + nt) * 8 + ks) * 64 + l) * 8]);
            short8 bV = *reinterpret_cast<const short8*>(&lds_b[(((4 + nt) * 8 + ks) * 64 + l) * 8]);
            accU[n] = __builtin_amdgcn_mfma_f32_32x32x16_bf16(afr, bU, accU[n], 0, 0, 0);
            accV[n] = __builtin_amdgcn_mfma_f32_32x32x16_bf16(afr, bV, accV[n], 0, 0, 0);
        }
    }

#pragma unroll
    for (int n = 0; n < 2; ++n) {
        const int col = wn * 64 + n * 32 + lc;
#pragma unroll
        for (int r = 0; r < 16; ++r) {
            const int row = (r & 3) + 8 * (r >> 2) + 4 * hi;
            const int node = base + row;
            if (node < Nn) {
                _Float16 hu = (_Float16)accU[n][r];
                _Float16 hv = (_Float16)accV[n][r];
                U[(size_t)node * HID + col] = __builtin_bit_cast(unsigned short, hu);
                V[(size_t)node * HID + col] = __builtin_bit_cast(unsigned short, hv);
            }
        }
    }
}

// ---------------------------------------------------------------------------
// 64-bucket histogram over tgt. bucket = min(63, (int)(t * bscale)),
// bscale = 64/Nn (monotone, balanced for uniform tgt). Identical expression
// in hist and scatter -> identical bucketing.
// ---------------------------------------------------------------------------
__global__ __launch_bounds__(256) void hist64_kernel(
    const void* __restrict__ src_raw, const void* __restrict__ tgt_raw,
    int E, float bscale, int* __restrict__ gh)
{
    __shared__ int lh[64];
    const int tid = threadIdx.x;
    if (tid < 64) lh[tid] = 0;
    __syncthreads();

    int i64f = 1;
    {
        const int* s32 = (const int*)src_raw;
#pragma unroll
        for (int i = 1; i < 32; i += 2) i64f &= (s32[i] == 0);
    }
    const int stride = gridDim.x * 256;
    for (int e = blockIdx.x * 256 + tid; e < E; e += stride) {
        int t = i64f ? (int)((const long long*)tgt_raw)[e]
                     : ((const int*)tgt_raw)[e];
        int b = (int)((float)t * bscale);
        b = b < 0 ? 0 : (b > 63 ? 63 : b);
        atomicAdd(&lh[b], 1);
    }
    __syncthreads();
    if (tid < 64 && lh[tid]) atomicAdd(&gh[tid], lh[tid]);
}

// ---------------------------------------------------------------------------
// Bucket offsets: goff[64] (exclusive prefix) and off8[9] (per-XCD ranges).
// ---------------------------------------------------------------------------
__global__ void off64_kernel(const int* __restrict__ gh,
                             int* __restrict__ goff, int* __restrict__ off8) {
    __shared__ int h[64];
    const int t = threadIdx.x;
    h[t] = gh[t];
    __syncthreads();
    if (t == 0) {
        int acc = 0;
        for (int b = 0; b < 64; ++b) {
            goff[b] = acc;
            if ((b & 7) == 0) off8[b >> 3] = acc;
            acc += h[b];
        }
        off8[8] = acc;
    }
}

// ---------------------------------------------------------------------------
// LDS-staged partition scatter: 2048 edges/block; per-block bucket counts,
// 64 per-block cursor atomics, LDS placement, semi-coalesced run writes.
// ---------------------------------------------------------------------------
__global__ __launch_bounds__(256) void scatter64_kernel(
    const void* __restrict__ src_raw, const void* __restrict__ tgt_raw,
    int E, float bscale,
    const int* __restrict__ goff, int* __restrict__ cursor,
    int* __restrict__ ss, int* __restrict__ tt, int* __restrict__ ei)
{
    __shared__ int lh[64], lh2[64], lo[64], grb[64], go[64];
    __shared__ int sS[2048], sT[2048], sE[2048], bk[2048];

    const int tid = threadIdx.x;
    int i64f = 1;
    {
        const int* s32 = (const int*)src_raw;
#pragma unroll
        for (int i = 1; i < 32; i += 2) i64f &= (s32[i] == 0);
    }
    if (tid < 64) { lh[tid] = 0; lh2[tid] = 0; go[tid] = goff[tid]; }
    __syncthreads();

    const int base = blockIdx.x * 2048;
    int myS[8], myT[8], myB[8];
#pragma unroll
    for (int k = 0; k < 8; ++k) {
        const int e = base + k * 256 + tid;
        myB[k] = -1;
        if (e < E) {
            int s, t;
            if (i64f) {
                s = (int)((const long long*)src_raw)[e];
                t = (int)((const long long*)tgt_raw)[e];
            } else {
                s = ((const int*)src_raw)[e];
                t = ((const int*)tgt_raw)[e];
            }
            int b = (int)((float)t * bscale);
            b = b < 0 ? 0 : (b > 63 ? 63 : b);
            myS[k] = s; myT[k] = t; myB[k] = b;
            atomicAdd(&lh[b], 1);
        }
    }
    __syncthreads();
    if (tid == 0) {
        int acc = 0;
        for (int b = 0; b < 64; ++b) { lo[b] = acc; acc += lh[b]; }
    }
    __syncthreads();
    if (tid < 64 && lh[tid] > 0) grb[tid] = atomicAdd(&cursor[tid], lh[tid]);
    __syncthreads();
#pragma unroll
    for (int k = 0; k < 8; ++k) {
        if (myB[k] >= 0) {
            const int b = myB[k];
            const int pl = lo[b] + atomicAdd(&lh2[b], 1);
            sS[pl] = myS[k];
            sT[pl] = myT[k];
            sE[pl] = base + k * 256 + tid;
            bk[pl] = b;
        }
    }
    __syncthreads();
    const int total = lo[63] + lh[63];
    for (int i = tid; i < total; i += 256) {
        const int b = bk[i];
        const int dst = go[b] + grb[b] + (i - lo[b]);
        ss[dst] = sS[i];
        tt[dst] = sT[i];
        ei[dst] = sE[i];
    }
}

// ---------------------------------------------------------------------------
// Partitioned edge pass: XCD p (blockIdx%8, round-robin dispatch) processes
// edges [off8[p], off8[p+1]) via grid-stride -> its V-slice stays in its L2.
// fp16 packed math as R12.
// ---------------------------------------------------------------------------
__global__ __launch_bounds__(256) void edge_pass_part_kernel(
    const unsigned short* __restrict__ U,
    const unsigned short* __restrict__ V,
    const int* __restrict__ ss,
    const int* __restrict__ tt,
    const int* __restrict__ ei,
    const int* __restrict__ off8,
    const float* __restrict__ b1,
    const float* __restrict__ W2,
    const float* __restrict__ b2,
    float* __restrict__ out,
    int per_x)
{
    const int tid = threadIdx.x;
    const int l   = tid & 63;
    const int wid = tid >> 6;
    const int le  = l >> 4;          // edge slot in group (0..3)
    const int lc  = l & 15;          // col group: cols [lc*8, lc*8+8)
    const int p   = blockIdx.x & 7;  // XCD (round-robin dispatch assumption)
    const int r   = blockIdx.x >> 3;

    const int pbeg = off8[p];
    const int pend = off8[p + 1];

    h2 b1p[4], w2p[4];
    {
        f32x4 a = *reinterpret_cast<const f32x4*>(b1 + lc * 8);
        f32x4 b = *reinterpret_cast<const f32x4*>(b1 + lc * 8 + 4);
        f32x4 c = *reinterpret_cast<const f32x4*>(W2 + lc * 8);
        f32x4 d = *reinterpret_cast<const f32x4*>(W2 + lc * 8 + 4);
#pragma unroll
        for (int j = 0; j < 2; ++j) {
            b1p[0][j] = (_Float16)a[j];     b1p[1][j] = (_Float16)a[2 + j];
            b1p[2][j] = (_Float16)b[j];     b1p[3][j] = (_Float16)b[2 + j];
            w2p[0][j] = (_Float16)c[j];     w2p[1][j] = (_Float16)c[2 + j];
            w2p[2][j] = (_Float16)d[j];     w2p[3][j] = (_Float16)d[2 + j];
        }
    }
    const float b2s = b2[0];
    const h2 zero2 = (h2)((_Float16)0.f);

    for (int base = pbeg + r * 64; base < pend; base += per_x * 64) {
        short8 ub[4], vb[4];
        int oid[4];
        bool live[4];
#pragma unroll
        for (int g = 0; g < 4; ++g) {
            int pos = base + wid * 16 + g * 4 + le;
            live[g] = (pos < pend);
            if (!live[g]) pos = base;
            const int s = ss[pos];
            const int t = tt[pos];
            oid[g] = ei[pos];
            ub[g] = *reinterpret_cast<const short8*>(U + (unsigned)s * HID + lc * 8);
            vb[g] = *reinterpret_cast<const short8*>(V + (unsigned)t * HID + lc * 8);
        }

#pragma unroll
        for (int g = 0; g < 4; ++g) {
            const unsigned int* uw = (const unsigned int*)&ub[g];
            const unsigned int* vw = (const unsigned int*)&vb[g];
            h2 s2 = zero2;
#pragma unroll
            for (int j = 0; j < 4; ++j) {
                h2 hu = __builtin_bit_cast(h2, uw[j]);
                h2 hv = __builtin_bit_cast(h2, vw[j]);
                h2 h  = hu + hv + b1p[j];
                h = __builtin_elementwise_max(h, zero2);
                s2 = s2 + h * w2p[j];
            }
            float s = (float)s2[0] + (float)s2[1];
#pragma unroll
            for (int w = 1; w < 16; w <<= 1)
                s += __shfl_xor(s, w, 16);
            if (lc == 0 && live[g])
                out[oid[g]] = s + b2s;
        }
    }
}

// ---------------------------------------------------------------------------
// Unsorted edge pass (R12 path, fallback when ws can't hold partition arrays).
// ---------------------------------------------------------------------------
__global__ __launch_bounds__(256) void edge_pass_kernel(
    const unsigned short* __restrict__ U,
    const unsigned short* __restrict__ V,
    const void* __restrict__ src_raw,
    const void* __restrict__ tgt_raw,
    const float* __restrict__ b1,
    const float* __restrict__ W2,
    const float* __restrict__ b2,
    float* __restrict__ out,
    int E)
{
    const int tid = threadIdx.x;
    const int l   = tid & 63;
    const int wid = tid >> 6;
    const int le  = l >> 4;
    const int lc  = l & 15;

    int oddw = 0;
    {
        const int* s32 = (const int*)src_raw;
        if (l < 32) oddw = s32[2 * l + 1];
    }
    const bool i64f = (__ballot(oddw != 0) == 0ULL);

    h2 b1p[4], w2p[4];
    {
        f32x4 a = *reinterpret_cast<const f32x4*>(b1 + lc * 8);
        f32x4 b = *reinterpret_cast<const f32x4*>(b1 + lc * 8 + 4);
        f32x4 c = *reinterpret_cast<const f32x4*>(W2 + lc * 8);
        f32x4 d = *reinterpret_cast<const f32x4*>(W2 + lc * 8 + 4);
#pragma unroll
        for (int j = 0; j < 2; ++j) {
            b1p[0][j] = (_Float16)a[j];     b1p[1][j] = (_Float16)a[2 + j];
            b1p[2][j] = (_Float16)b[j];     b1p[3][j] = (_Float16)b[2 + j];
            w2p[0][j] = (_Float16)c[j];     w2p[1][j] = (_Float16)c[2 + j];
            w2p[2][j] = (_Float16)d[j];     w2p[3][j] = (_Float16)d[2 + j];
        }
    }
    const float b2s = b2[0];
    const h2 zero2 = (h2)((_Float16)0.f);

    const long long ebase = ((long long)blockIdx.x * 4 + wid) * 16;

    short8 ub[4], vb[4];
#pragma unroll
    for (int g = 0; g < 4; ++g) {
        long long e = ebase + g * 4 + le;
        if (e >= E) e = E - 1;
        long long si, ti;
        if (i64f) {
            si = ((const long long*)src_raw)[e];
            ti = ((const long long*)tgt_raw)[e];
        } else {
            si = ((const int*)src_raw)[e];
            ti = ((const int*)tgt_raw)[e];
        }
        ub[g] = *reinterpret_cast<const short8*>(U + (unsigned)si * HID + lc * 8);
        vb[g] = *reinterpret_cast<const short8*>(V + (unsigned)ti * HID + lc * 8);
    }

#pragma unroll
    for (int g = 0; g < 4; ++g) {
        const unsigned int* uw = (const unsigned int*)&ub[g];
        const unsigned int* vw = (const unsigned int*)&vb[g];
        h2 s2 = zero2;
#pragma unroll
        for (int j = 0; j < 4; ++j) {
            h2 hu = __builtin_bit_cast(h2, uw[j]);
            h2 hv = __builtin_bit_cast(h2, vw[j]);
            h2 h  = hu + hv + b1p[j];
            h = __builtin_elementwise_max(h, zero2);
            s2 = s2 + h * w2p[j];
        }
        float s = (float)s2[0] + (float)s2[1];
#pragma unroll
        for (int w = 1; w < 16; w <<= 1)
            s += __shfl_xor(s, w, 16);
        const long long e = ebase + g * 4 + le;
        if (lc == 0 && e < E)
            out[e] = s + b2s;
    }
}

// ===========================================================================
// FALLBACK PATH (R3): MFMA over gathered rows (bf16), for tiny ws.
// ===========================================================================

__global__ void pack_w1_kernel(const float* __restrict__ W1, short* __restrict__ bpk) {
    int t = blockIdx.x * 256 + threadIdx.x;
    int f = (t >> 6) & 7;
    int l = t & 63;
    int n = t >> 9;
    int c = l & 15, kb = l >> 4;
    int k0 = f * 32 + kb * 8;
    short8 v;
#pragma unroll
    for (int j = 0; j < 8; ++j)
        v[j] = f2bf(W1[(k0 + j) * HID + n * 16 + c]);
    *reinterpret_cast<short8*>(&bpk[t * 8]) = v;
}

__global__ __launch_bounds__(256) void conv_emb_kernel(
    const float* __restrict__ emb, short* __restrict__ bemb, int n8) {
    int i = blockIdx.x * 256 + threadIdx.x;
    if (i >= n8) return;
    f32x4 x0 = *reinterpret_cast<const f32x4*>(emb + (size_t)i * 8);
    f32x4 x1 = *reinterpret_cast<const f32x4*>(emb + (size_t)i * 8 + 4);
    short8 v;
#pragma unroll
    for (int j = 0; j < 4; ++j) {
        v[j]     = f2bf(x0[j]);
        v[4 + j] = f2bf(x1[j]);
    }
    *reinterpret_cast<short8*>(&bemb[(size_t)i * 8]) = v;
}

template <int MODE>
__global__ __launch_bounds__(512, 4) void edge_head_kernel(
    const float* __restrict__ emb,
    const short* __restrict__ bemb,
    const void* __restrict__ src_raw,
    const void* __restrict__ tgt_raw,
    const float* __restrict__ W1,
    const float* __restrict__ b1,
    const float* __restrict__ W2,
    const float* __restrict__ b2,
    const short* __restrict__ bpk,
    float* __restrict__ out,
    int E)
{
    __shared__ short lds_b[32768];

    const int tid = threadIdx.x;

    int i64f = 1;
    {
        const int* s32 = (const int*)src_raw;
#pragma unroll
        for (int i = 1; i < 32; i += 2) i64f &= (s32[i] == 0);
    }

    if (MODE != 2) {
        const u32x4* g = (const u32x4*)bpk;
        u32x4* d = (u32x4*)lds_b;
#pragma unroll
        for (int i = 0; i < 8; ++i) d[i * 512 + tid] = g[i * 512 + tid];
    } else {
        for (int i = 0; i < 64; ++i) {
            int idx = i * 512 + tid;
            int col = idx & 127;
            int k   = idx >> 7;
            int n = col >> 4, cc = col & 15;
            int f = k >> 5, kb = (k >> 3) & 3, j = k & 7;
            int l2 = kb * 16 + cc;
            lds_b[(((n * 8 + f) * 64 + l2) << 3) + j] = f2bf(W1[idx]);
        }
    }
    __syncthreads();

    const int l = tid & 63;
    const int wid = tid >> 6;
    const int c = l & 15;
    const int g = l >> 4;
    const long long e0 = (long long)blockIdx.x * 256 + wid * 32;

    unsigned so[2], to[2];
#pragma unroll
    for (int m = 0; m < 2; ++m) {
        long long e = e0 + m * 16 + c;
        if (e >= E) e = E - 1;
        long long si, ti;
        if (i64f) {
            si = ((const long long*)src_raw)[e];
            ti = ((const long long*)tgt_raw)[e];
        } else {
            si = ((const int*)src_raw)[e];
            ti = ((const int*)tgt_raw)[e];
        }
        so[m] = (unsigned)si * HID;
        to[m] = (unsigned)ti * HID;
    }

    f32x4 acc[2][8];
#pragma unroll
    for (int m = 0; m < 2; ++m)
#pragma unroll
        for (int n = 0; n < 8; ++n)
            acc[m][n] = (f32x4){0.f, 0.f, 0.f, 0.f};

    const int koff = g * 8;
#pragma unroll
    for (int f = 0; f < 8; ++f) {
        short8 afr[2];
        const int k0 = (f & 3) * 32 + koff;
#pragma unroll
        for (int m = 0; m < 2; ++m) {
            const unsigned off = (f < 4 ? so[m] : to[m]) + k0;
            if (MODE == 0) {
                afr[m] = *reinterpret_cast<const short8*>(bemb + off);
            } else {
                f32x4 x0 = *reinterpret_cast<const f32x4*>(emb + off);
                f32x4 x1 = *reinterpret_cast<const f32x4*>(emb + off + 4);
                short8 t;
#pragma unroll
                for (int j = 0; j < 4; ++j) {
                    t[j]     = f2bf(x0[j]);
                    t[4 + j] = f2bf(x1[j]);
                }
                afr[m] = t;
            }
        }
#pragma unroll
        for (int n = 0; n < 8; ++n) {
            short8 bfr = *reinterpret_cast<const short8*>(&lds_b[((n * 8 + f) * 64 + l) * 8]);
#pragma unroll
            for (int m = 0; m < 2; ++m)
                acc[m][n] = __builtin_amdgcn_mfma_f32_16x16x32_bf16(afr[m], bfr, acc[m][n], 0, 0, 0);
        }
    }

    float b1v[8], w2v[8];
#pragma unroll
    for (int n = 0; n < 8; ++n) {
        b1v[n] = b1[n * 16 + c];
        w2v[n] = W2[n * 16 + c];
    }
    const float b2s = b2[0];

#pragma unroll
    for (int m = 0; m < 2; ++m) {
        float s[4] = {0.f, 0.f, 0.f, 0.f};
#pragma unroll
        for (int n = 0; n < 8; ++n) {
#pragma unroll
            for (int r = 0; r < 4; ++r)
                s[r] += fmaxf(acc[m][n][r] + b1v[n], 0.f) * w2v[n];
        }
#pragma unroll
        for (int w = 1; w < 16; w <<= 1) {
#pragma unroll
            for (int r = 0; r < 4; ++r)
                s[r] += __shfl_xor(s[r], w, 16);
        }
        if (c == 0) {
            const long long eb = e0 + m * 16 + g * 4;
#pragma unroll
            for (int r = 0; r < 4; ++r)
                if (eb + r < E) out[eb + r] = s[r] + b2s;
        }
    }
}

extern "C" void kernel_launch(void* const* d_in, const int* in_sizes, int n_in,
                              void* d_out, int out_size, void* d_ws, size_t ws_size,
                              hipStream_t stream) {
    const float* emb = (const float*)d_in[0];
    const void*  src = d_in[1];
    const void*  tgt = d_in[2];
    // d_in[3] = edge_type_idx (selector; params passed are already the selected ones)
    const float* W1 = (const float*)d_in[4];
    const float* b1 = (const float*)d_in[5];
    const float* W2 = (const float*)d_in[6];
    const float* b2 = (const float*)d_in[7];
    float* out = (float*)d_out;

    const int E  = in_sizes[1];
    const int Nn = in_sizes[0] / HID;

    const size_t uv_bytes = (size_t)Nn * HID * sizeof(short);
    // partitioned layout: bpk2 64K | gh 256 | cursor 256 | goff 256 | off8 256
    //                     | pad to 64K+4K | U | V | ss | tt | ei
    const size_t off_gh   = 65536;
    const size_t off_cur  = off_gh + 256;
    const size_t off_goff = off_cur + 256;
    const size_t off_off8 = off_goff + 256;
    const size_t off_U    = 65536 + 4096;
    const size_t off_V    = off_U + uv_bytes;
    const size_t off_ss   = off_V + uv_bytes;
    const size_t off_tt   = off_ss + (size_t)E * 4;
    const size_t off_ei   = off_tt + (size_t)E * 4;
    const size_t need_part = off_ei + (size_t)E * 4;
    const size_t need_uv   = 65536 + 2 * uv_bytes;
    const size_t need_old  = 65536 + (size_t)in_sizes[0] * sizeof(short);

    if (ws_size >= need_part && E >= 4096) {
        short*          bpk2   = (short*)d_ws;
        int*            gh     = (int*)((char*)d_ws + off_gh);
        int*            cursor = (int*)((char*)d_ws + off_cur);
        int*            goff   = (int*)((char*)d_ws + off_goff);
        int*            off8   = (int*)((char*)d_ws + off_off8);
        unsigned short* U      = (unsigned short*)((char*)d_ws + off_U);
        unsigned short* Vv     = (unsigned short*)((char*)d_ws + off_V);
        int*            ss     = (int*)((char*)d_ws + off_ss);
        int*            tt     = (int*)((char*)d_ws + off_tt);
        int*            ei     = (int*)((char*)d_ws + off_ei);

        const float bscale = 63.9999f / (float)Nn;

        hipMemsetAsync((char*)d_ws + off_gh, 0, 512, stream);   // gh + cursor
        pack_w1_uv_kernel<<<16, 256, 0, stream>>>(W1, bpk2);
        hist64_kernel<<<256, 256, 0, stream>>>(src, tgt, E, bscale, gh);
        uv_kernel<<<(Nn + 127) / 128, 512, 0, stream>>>(emb, bpk2, U, Vv, Nn);
        off64_kernel<<<1, 64, 0, stream>>>(gh, goff, off8);
        scatter64_kernel<<<(E + 2047) / 2048, 256, 0, stream>>>(
            src, tgt, E, bscale, goff, cursor, ss, tt, ei);
        const int per_x = (E / 8 + 4096) / 64 + 2;
        edge_pass_part_kernel<<<per_x * 8, 256, 0, stream>>>(
            U, Vv, ss, tt, ei, off8, b1, W2, b2, out, per_x);
        return;
    }

    if (ws_size >= need_uv) {
        short*          bpk2 = (short*)d_ws;
        unsigned short* U    = (unsigned short*)((char*)d_ws + 65536);
        unsigned short* Vv   = (unsigned short*)((char*)d_ws + 65536 + uv_bytes);

        pack_w1_uv_kernel<<<16, 256, 0, stream>>>(W1, bpk2);
        uv_kernel<<<(Nn + 127) / 128, 512, 0, stream>>>(emb, bpk2, U, Vv, Nn);
        edge_pass_kernel<<<(E + 63) / 64, 256, 0, stream>>>(U, Vv, src, tgt, b1, W2, b2, out, E);
        return;
    }

    // ---- fallback: R3 gathered-MFMA path
    short* bpk  = (short*)d_ws;
    short* bemb = (short*)((char*)d_ws + 65536);

    int mode;
    if (ws_size >= need_old)        mode = 0;
    else if (ws_size >= 65536)      mode = 1;
    else                            mode = 2;

    if (mode != 2)
        pack_w1_kernel<<<16, 256, 0, stream>>>(W1, bpk);
    if (mode == 0) {
        const int n8 = in_sizes[0] / 8;
        conv_emb_kernel<<<(n8 + 255) / 256, 256, 0, stream>>>(emb, bemb, n8);
    }

    const int grid = (E + 255) / 256;
    if (mode == 0)
        edge_head_kernel<0><<<grid, 512, 0, stream>>>(emb, bemb, src, tgt, W1, b1, W2, b2, bpk, out, E);
    else if (mode == 1)
        edge_head_kernel<1><<<grid, 512, 0, stream>>>(emb, bemb, src, tgt, W1, b1, W2, b2, bpk, out, E);
    else
        edge_head_kernel<2><<<grid, 512, 0, stream>>>(emb, bemb, src, tgt, W1, b1, W2, b2, bpk, out, E);
}

// Round 16
// 147.458 us; speedup vs baseline: 1.8420x; 1.0153x over previous
//
#include <hip/hip_runtime.h>
#include <hip/hip_bf16.h>

#define HID 128

typedef __attribute__((ext_vector_type(8))) short short8;
typedef __attribute__((ext_vector_type(4))) float f32x4;
typedef __attribute__((ext_vector_type(16))) float f32x16;
typedef __attribute__((ext_vector_type(4))) unsigned int u32x4;
typedef __attribute__((ext_vector_type(2))) _Float16 h2;

__device__ __forceinline__ short f2bf(float x) {
    __bf16 b = (__bf16)x;
    return __builtin_bit_cast(short, b);
}

// ===========================================================================
// FACTORED PATH: U = emb@W1[:128], V = emb@W1[128:] (dense per-node GEMM),
// then out[e] = relu(U[src]+V[tgt]+b1)@W2 + b2 (gather + packed-fp16 VALU).
// R16 = R15 structure with the partition overhead stripped: 5 dispatches,
// wave-parallel scans, int2-packed edge records.
// ===========================================================================

// ---------------------------------------------------------------------------
// Pack W1 halves into 32x32x16 MFMA-B fragment order (bf16), both halves.
// Block 0 also zeroes gh[64]+cursor[64] (saves a memset dispatch).
// ---------------------------------------------------------------------------
__global__ void pack_w1_uv_kernel(const float* __restrict__ W1, short* __restrict__ bpk2,
                                  int* __restrict__ zero128) {
    if (zero128 && blockIdx.x == 0 && threadIdx.x < 128) zero128[threadIdx.x] = 0;
    int t = blockIdx.x * 256 + threadIdx.x;   // 0..4095 = half*2048 + nt*512 + ks*64 + l
    int l    = t & 63;
    int ks   = (t >> 6) & 7;
    int nt   = (t >> 9) & 3;
    int half = t >> 11;
    int k0  = half * 128 + ks * 16 + (l >> 5) * 8;
    int col = nt * 32 + (l & 31);
    short8 v;
#pragma unroll
    for (int j = 0; j < 8; ++j)
        v[j] = f2bf(W1[(k0 + j) * HID + col]);
    *reinterpret_cast<short8*>(&bpk2[t * 8]) = v;
}

// ---------------------------------------------------------------------------
// UV precompute (fp16 output): mfma_f32_32x32x16_bf16, 128 nodes/block.
// ---------------------------------------------------------------------------
__global__ __launch_bounds__(512, 4) void uv_kernel(
    const float* __restrict__ emb,
    const short* __restrict__ bpk2,
    unsigned short* __restrict__ U,
    unsigned short* __restrict__ V,
    int Nn)
{
    __shared__ short lds_b[32768];

    const int tid = threadIdx.x;
    const int l   = tid & 63;
    const int wid = tid >> 6;
    const int wg  = wid >> 1;
    const int wn  = wid & 1;
    const int lc  = l & 31;
    const int hi  = l >> 5;

    {
        const u32x4* g = (const u32x4*)bpk2;
        u32x4* d = (u32x4*)lds_b;
#pragma unroll
        for (int i = 0; i < 8; ++i) d[i * 512 + tid] = g[i * 512 + tid];
    }
    __syncthreads();

    const int base = blockIdx.x * 128 + wg * 32;
    int nr = base + lc;
    if (nr >= Nn) nr = Nn - 1;

    f32x16 accU[2], accV[2];
#pragma unroll
    for (int n = 0; n < 2; ++n) { accU[n] = (f32x16)(0.f); accV[n] = (f32x16)(0.f); }

#pragma unroll
    for (int ks = 0; ks < 8; ++ks) {
        const float* p = emb + (size_t)nr * HID + ks * 16 + hi * 8;
        f32x4 x0 = *reinterpret_cast<const f32x4*>(p);
        f32x4 x1 = *reinterpret_cast<const f32x4*>(p + 4);
        short8 afr;
#pragma unroll
        for (int j = 0; j < 4; ++j) { afr[j] = f2bf(x0[j]); afr[4 + j] = f2bf(x1[j]); }
#pragma unroll
        for (int n = 0; n < 2; ++n) {
            const int nt = wn * 2 + n;
            short8 bU = *reinterpret_cast<const short8*>(&lds_b[(((0 + nt) * 8 + ks) * 64 + l) * 8]);
            short8 bV = *reinterpret_cast<const short8*>(&lds_b[(((4 + nt) * 8 + ks) * 64 + l) * 8]);
            accU[n] = __builtin_amdgcn_mfma_f32_32x32x16_bf16(afr, bU, accU[n], 0, 0, 0);
            accV[n] = __builtin_amdgcn_mfma_f32_32x32x16_bf16(afr, bV, accV[n], 0, 0, 0);
        }
    }

#pragma unroll
    for (int n = 0; n < 2; ++n) {
        const int col = wn * 64 + n * 32 + lc;
#pragma unroll
        for (int r = 0; r < 16; ++r) {
            const int row = (r & 3) + 8 * (r >> 2) + 4 * hi;
            const int node = base + row;
            if (node < Nn) {
                _Float16 hu = (_Float16)accU[n][r];
                _Float16 hv = (_Float16)accV[n][r];
                U[(size_t)node * HID + col] = __builtin_bit_cast(unsigned short, hu);
                V[(size_t)node * HID + col] = __builtin_bit_cast(unsigned short, hv);
            }
        }
    }
}

// ---------------------------------------------------------------------------
// 64-bucket histogram over tgt. bucket = clamp((int)(t*bscale), 0, 63).
// ---------------------------------------------------------------------------
__global__ __launch_bounds__(256) void hist64_kernel(
    const void* __restrict__ src_raw, const void* __restrict__ tgt_raw,
    int E, float bscale, int* __restrict__ gh)
{
    __shared__ int lh[64];
    const int tid = threadIdx.x;
    if (tid < 64) lh[tid] = 0;
    __syncthreads();

    int i64f = 1;
    {
        const int* s32 = (const int*)src_raw;
#pragma unroll
        for (int i = 1; i < 32; i += 2) i64f &= (s32[i] == 0);
    }
    const int stride = gridDim.x * 256;
    for (int e = blockIdx.x * 256 + tid; e < E; e += stride) {
        int t = i64f ? (int)((const long long*)tgt_raw)[e]
                     : ((const int*)tgt_raw)[e];
        int b = (int)((float)t * bscale);
        b = b < 0 ? 0 : (b > 63 ? 63 : b);
        atomicAdd(&lh[b], 1);
    }
    __syncthreads();
    if (tid < 64 && lh[tid]) atomicAdd(&gh[tid], lh[tid]);
}

// ---------------------------------------------------------------------------
// LDS-staged partition scatter, streamlined: wave-parallel scans (no serial
// prefix, no off64 kernel -- each block rescans gh), int2-packed records.
// ---------------------------------------------------------------------------
__global__ __launch_bounds__(256) void scatter64_kernel(
    const void* __restrict__ src_raw, const void* __restrict__ tgt_raw,
    int E, float bscale,
    const int* __restrict__ gh, int* __restrict__ cursor,
    int2* __restrict__ st, int* __restrict__ ei)
{
    __shared__ int lh[64], lh2[64], lo[64], grb[64], go[64];
    __shared__ int2 sST[2048];
    __shared__ int sE[2048];
    __shared__ unsigned char bkk[2048];

    const int tid = threadIdx.x;
    int i64f = 1;
    {
        const int* s32 = (const int*)src_raw;
#pragma unroll
        for (int i = 1; i < 32; i += 2) i64f &= (s32[i] == 0);
    }
    if (tid < 64) { lh[tid] = 0; lh2[tid] = 0; }
    __syncthreads();

    const int base = blockIdx.x * 2048;
    int myS[8], myT[8], myB[8];
#pragma unroll
    for (int k = 0; k < 8; ++k) {
        const int e = base + k * 256 + tid;
        myB[k] = -1;
        if (e < E) {
            int s, t;
            if (i64f) {
                s = (int)((const long long*)src_raw)[e];
                t = (int)((const long long*)tgt_raw)[e];
            } else {
                s = ((const int*)src_raw)[e];
                t = ((const int*)tgt_raw)[e];
            }
            int b = (int)((float)t * bscale);
            b = b < 0 ? 0 : (b > 63 ? 63 : b);
            myS[k] = s; myT[k] = t; myB[k] = b;
            atomicAdd(&lh[b], 1);
        }
    }
    __syncthreads();
    if (tid < 64) {
        // wave-parallel exclusive scans of lh (block-local) and gh (global)
        int vl = lh[tid], vg = gh[tid];
        int il = vl, ig = vg;
#pragma unroll
        for (int off = 1; off < 64; off <<= 1) {
            int xl = __shfl_up(il, off, 64);
            int xg = __shfl_up(ig, off, 64);
            if (tid >= off) { il += xl; ig += xg; }
        }
        lo[tid] = il - vl;
        go[tid] = ig - vg;
        grb[tid] = (vl > 0) ? atomicAdd(&cursor[tid], vl) : 0;
    }
    __syncthreads();
#pragma unroll
    for (int k = 0; k < 8; ++k) {
        if (myB[k] >= 0) {
            const int b = myB[k];
            const int pl = lo[b] + atomicAdd(&lh2[b], 1);
            sST[pl] = make_int2(myS[k], myT[k]);
            sE[pl] = base + k * 256 + tid;
            bkk[pl] = (unsigned char)b;
        }
    }
    __syncthreads();
    const int total = lo[63] + lh[63];
    for (int i = tid; i < total; i += 256) {
        const int b = bkk[i];
        const int dst = go[b] + grb[b] + (i - lo[b]);
        st[dst] = sST[i];
        ei[dst] = sE[i];
    }
}

// ---------------------------------------------------------------------------
// Partitioned edge pass: XCD p (blockIdx%8, round-robin dispatch) processes
// edges [off8[p], off8[p+1]); off8 derived in-block from gh by a wave scan.
// fp16 packed math as R12.
// ---------------------------------------------------------------------------
__global__ __launch_bounds__(256) void edge_pass_part_kernel(
    const unsigned short* __restrict__ U,
    const unsigned short* __restrict__ V,
    const int2* __restrict__ st,
    const int* __restrict__ ei,
    const int* __restrict__ gh,
    const float* __restrict__ b1,
    const float* __restrict__ W2,
    const float* __restrict__ b2,
    float* __restrict__ out,
    int per_x)
{
    __shared__ int sh_off8[9];

    const int tid = threadIdx.x;
    if (tid < 64) {
        int v = gh[tid];
        int inc = v;
#pragma unroll
        for (int off = 1; off < 64; off <<= 1) {
            int x = __shfl_up(inc, off, 64);
            if (tid >= off) inc += x;
        }
        if ((tid & 7) == 0) sh_off8[tid >> 3] = inc - v;
        if (tid == 63) sh_off8[8] = inc;
    }
    __syncthreads();

    const int l   = tid & 63;
    const int wid = tid >> 6;
    const int le  = l >> 4;          // edge slot in group (0..3)
    const int lc  = l & 15;          // col group: cols [lc*8, lc*8+8)
    const int p   = blockIdx.x & 7;  // XCD (round-robin dispatch)
    const int r   = blockIdx.x >> 3;

    const int pbeg = sh_off8[p];
    const int pend = sh_off8[p + 1];

    h2 b1p[4], w2p[4];
    {
        f32x4 a = *reinterpret_cast<const f32x4*>(b1 + lc * 8);
        f32x4 b = *reinterpret_cast<const f32x4*>(b1 + lc * 8 + 4);
        f32x4 c = *reinterpret_cast<const f32x4*>(W2 + lc * 8);
        f32x4 d = *reinterpret_cast<const f32x4*>(W2 + lc * 8 + 4);
#pragma unroll
        for (int j = 0; j < 2; ++j) {
            b1p[0][j] = (_Float16)a[j];     b1p[1][j] = (_Float16)a[2 + j];
            b1p[2][j] = (_Float16)b[j];     b1p[3][j] = (_Float16)b[2 + j];
            w2p[0][j] = (_Float16)c[j];     w2p[1][j] = (_Float16)c[2 + j];
            w2p[2][j] = (_Float16)d[j];     w2p[3][j] = (_Float16)d[2 + j];
        }
    }
    const float b2s = b2[0];
    const h2 zero2 = (h2)((_Float16)0.f);

    for (int base = pbeg + r * 64; base < pend; base += per_x * 64) {
        short8 ub[4], vb[4];
        int oid[4];
        bool live[4];
#pragma unroll
        for (int g = 0; g < 4; ++g) {
            int pos = base + wid * 16 + g * 4 + le;
            live[g] = (pos < pend);
            if (!live[g]) pos = base;
            const int2 pr = st[pos];
            oid[g] = ei[pos];
            ub[g] = *reinterpret_cast<const short8*>(U + (unsigned)pr.x * HID + lc * 8);
            vb[g] = *reinterpret_cast<const short8*>(V + (unsigned)pr.y * HID + lc * 8);
        }

#pragma unroll
        for (int g = 0; g < 4; ++g) {
            const unsigned int* uw = (const unsigned int*)&ub[g];
            const unsigned int* vw = (const unsigned int*)&vb[g];
            h2 s2 = zero2;
#pragma unroll
            for (int j = 0; j < 4; ++j) {
                h2 hu = __builtin_bit_cast(h2, uw[j]);
                h2 hv = __builtin_bit_cast(h2, vw[j]);
                h2 h  = hu + hv + b1p[j];
                h = __builtin_elementwise_max(h, zero2);
                s2 = s2 + h * w2p[j];
            }
            float s = (float)s2[0] + (float)s2[1];
#pragma unroll
            for (int w = 1; w < 16; w <<= 1)
                s += __shfl_xor(s, w, 16);
            if (lc == 0 && live[g])
                out[oid[g]] = s + b2s;
        }
    }
}

// ---------------------------------------------------------------------------
// Unsorted edge pass (R12 path, fallback when ws can't hold partition arrays).
// ---------------------------------------------------------------------------
__global__ __launch_bounds__(256) void edge_pass_kernel(
    const unsigned short* __restrict__ U,
    const unsigned short* __restrict__ V,
    const void* __restrict__ src_raw,
    const void* __restrict__ tgt_raw,
    const float* __restrict__ b1,
    const float* __restrict__ W2,
    const float* __restrict__ b2,
    float* __restrict__ out,
    int E)
{
    const int tid = threadIdx.x;
    const int l   = tid & 63;
    const int wid = tid >> 6;
    const int le  = l >> 4;
    const int lc  = l & 15;

    int oddw = 0;
    {
        const int* s32 = (const int*)src_raw;
        if (l < 32) oddw = s32[2 * l + 1];
    }
    const bool i64f = (__ballot(oddw != 0) == 0ULL);

    h2 b1p[4], w2p[4];
    {
        f32x4 a = *reinterpret_cast<const f32x4*>(b1 + lc * 8);
        f32x4 b = *reinterpret_cast<const f32x4*>(b1 + lc * 8 + 4);
        f32x4 c = *reinterpret_cast<const f32x4*>(W2 + lc * 8);
        f32x4 d = *reinterpret_cast<const f32x4*>(W2 + lc * 8 + 4);
#pragma unroll
        for (int j = 0; j < 2; ++j) {
            b1p[0][j] = (_Float16)a[j];     b1p[1][j] = (_Float16)a[2 + j];
            b1p[2][j] = (_Float16)b[j];     b1p[3][j] = (_Float16)b[2 + j];
            w2p[0][j] = (_Float16)c[j];     w2p[1][j] = (_Float16)c[2 + j];
            w2p[2][j] = (_Float16)d[j];     w2p[3][j] = (_Float16)d[2 + j];
        }
    }
    const float b2s = b2[0];
    const h2 zero2 = (h2)((_Float16)0.f);

    const long long ebase = ((long long)blockIdx.x * 4 + wid) * 16;

    short8 ub[4], vb[4];
#pragma unroll
    for (int g = 0; g < 4; ++g) {
        long long e = ebase + g * 4 + le;
        if (e >= E) e = E - 1;
        long long si, ti;
        if (i64f) {
            si = ((const long long*)src_raw)[e];
            ti = ((const long long*)tgt_raw)[e];
        } else {
            si = ((const int*)src_raw)[e];
            ti = ((const int*)tgt_raw)[e];
        }
        ub[g] = *reinterpret_cast<const short8*>(U + (unsigned)si * HID + lc * 8);
        vb[g] = *reinterpret_cast<const short8*>(V + (unsigned)ti * HID + lc * 8);
    }

#pragma unroll
    for (int g = 0; g < 4; ++g) {
        const unsigned int* uw = (const unsigned int*)&ub[g];
        const unsigned int* vw = (const unsigned int*)&vb[g];
        h2 s2 = zero2;
#pragma unroll
        for (int j = 0; j < 4; ++j) {
            h2 hu = __builtin_bit_cast(h2, uw[j]);
            h2 hv = __builtin_bit_cast(h2, vw[j]);
            h2 h  = hu + hv + b1p[j];
            h = __builtin_elementwise_max(h, zero2);
            s2 = s2 + h * w2p[j];
        }
        float s = (float)s2[0] + (float)s2[1];
#pragma unroll
        for (int w = 1; w < 16; w <<= 1)
            s += __shfl_xor(s, w, 16);
        const long long e = ebase + g * 4 + le;
        if (lc == 0 && e < E)
            out[e] = s + b2s;
    }
}

// ===========================================================================
// FALLBACK PATH (R3): MFMA over gathered rows (bf16), for tiny ws.
// ===========================================================================

__global__ void pack_w1_kernel(const float* __restrict__ W1, short* __restrict__ bpk) {
    int t = blockIdx.x * 256 + threadIdx.x;
    int f = (t >> 6) & 7;
    int l = t & 63;
    int n = t >> 9;
    int c = l & 15, kb = l >> 4;
    int k0 = f * 32 + kb * 8;
    short8 v;
#pragma unroll
    for (int j = 0; j < 8; ++j)
        v[j] = f2bf(W1[(k0 + j) * HID + n * 16 + c]);
    *reinterpret_cast<short8*>(&bpk[t * 8]) = v;
}

__global__ __launch_bounds__(256) void conv_emb_kernel(
    const float* __restrict__ emb, short* __restrict__ bemb, int n8) {
    int i = blockIdx.x * 256 + threadIdx.x;
    if (i >= n8) return;
    f32x4 x0 = *reinterpret_cast<const f32x4*>(emb + (size_t)i * 8);
    f32x4 x1 = *reinterpret_cast<const f32x4*>(emb + (size_t)i * 8 + 4);
    short8 v;
#pragma unroll
    for (int j = 0; j < 4; ++j) {
        v[j]     = f2bf(x0[j]);
        v[4 + j] = f2bf(x1[j]);
    }
    *reinterpret_cast<short8*>(&bemb[(size_t)i * 8]) = v;
}

template <int MODE>
__global__ __launch_bounds__(512, 4) void edge_head_kernel(
    const float* __restrict__ emb,
    const short* __restrict__ bemb,
    const void* __restrict__ src_raw,
    const void* __restrict__ tgt_raw,
    const float* __restrict__ W1,
    const float* __restrict__ b1,
    const float* __restrict__ W2,
    const float* __restrict__ b2,
    const short* __restrict__ bpk,
    float* __restrict__ out,
    int E)
{
    __shared__ short lds_b[32768];

    const int tid = threadIdx.x;

    int i64f = 1;
    {
        const int* s32 = (const int*)src_raw;
#pragma unroll
        for (int i = 1; i < 32; i += 2) i64f &= (s32[i] == 0);
    }

    if (MODE != 2) {
        const u32x4* g = (const u32x4*)bpk;
        u32x4* d = (u32x4*)lds_b;
#pragma unroll
        for (int i = 0; i < 8; ++i) d[i * 512 + tid] = g[i * 512 + tid];
    } else {
        for (int i = 0; i < 64; ++i) {
            int idx = i * 512 + tid;
            int col = idx & 127;
            int k   = idx >> 7;
            int n = col >> 4, cc = col & 15;
            int f = k >> 5, kb = (k >> 3) & 3, j = k & 7;
            int l2 = kb * 16 + cc;
            lds_b[(((n * 8 + f) * 64 + l2) << 3) + j] = f2bf(W1[idx]);
        }
    }
    __syncthreads();

    const int l = tid & 63;
    const int wid = tid >> 6;
    const int c = l & 15;
    const int g = l >> 4;
    const long long e0 = (long long)blockIdx.x * 256 + wid * 32;

    unsigned so[2], to[2];
#pragma unroll
    for (int m = 0; m < 2; ++m) {
        long long e = e0 + m * 16 + c;
        if (e >= E) e = E - 1;
        long long si, ti;
        if (i64f) {
            si = ((const long long*)src_raw)[e];
            ti = ((const long long*)tgt_raw)[e];
        } else {
            si = ((const int*)src_raw)[e];
            ti = ((const int*)tgt_raw)[e];
        }
        so[m] = (unsigned)si * HID;
        to[m] = (unsigned)ti * HID;
    }

    f32x4 acc[2][8];
#pragma unroll
    for (int m = 0; m < 2; ++m)
#pragma unroll
        for (int n = 0; n < 8; ++n)
            acc[m][n] = (f32x4){0.f, 0.f, 0.f, 0.f};

    const int koff = g * 8;
#pragma unroll
    for (int f = 0; f < 8; ++f) {
        short8 afr[2];
        const int k0 = (f & 3) * 32 + koff;
#pragma unroll
        for (int m = 0; m < 2; ++m) {
            const unsigned off = (f < 4 ? so[m] : to[m]) + k0;
            if (MODE == 0) {
                afr[m] = *reinterpret_cast<const short8*>(bemb + off);
            } else {
                f32x4 x0 = *reinterpret_cast<const f32x4*>(emb + off);
                f32x4 x1 = *reinterpret_cast<const f32x4*>(emb + off + 4);
                short8 t;
#pragma unroll
                for (int j = 0; j < 4; ++j) {
                    t[j]     = f2bf(x0[j]);
                    t[4 + j] = f2bf(x1[j]);
                }
                afr[m] = t;
            }
        }
#pragma unroll
        for (int n = 0; n < 8; ++n) {
            short8 bfr = *reinterpret_cast<const short8*>(&lds_b[((n * 8 + f) * 64 + l) * 8]);
#pragma unroll
            for (int m = 0; m < 2; ++m)
                acc[m][n] = __builtin_amdgcn_mfma_f32_16x16x32_bf16(afr[m], bfr, acc[m][n], 0, 0, 0);
        }
    }

    float b1v[8], w2v[8];
#pragma unroll
    for (int n = 0; n < 8; ++n) {
        b1v[n] = b1[n * 16 + c];
        w2v[n] = W2[n * 16 + c];
    }
    const float b2s = b2[0];

#pragma unroll
    for (int m = 0; m < 2; ++m) {
        float s[4] = {0.f, 0.f, 0.f, 0.f};
#pragma unroll
        for (int n = 0; n < 8; ++n) {
#pragma unroll
            for (int r = 0; r < 4; ++r)
                s[r] += fmaxf(acc[m][n][r] + b1v[n], 0.f) * w2v[n];
        }
#pragma unroll
        for (int w = 1; w < 16; w <<= 1) {
#pragma unroll
            for (int r = 0; r < 4; ++r)
                s[r] += __shfl_xor(s[r], w, 16);
        }
        if (c == 0) {
            const long long eb = e0 + m * 16 + g * 4;
#pragma unroll
            for (int r = 0; r < 4; ++r)
                if (eb + r < E) out[eb + r] = s[r] + b2s;
        }
    }
}

extern "C" void kernel_launch(void* const* d_in, const int* in_sizes, int n_in,
                              void* d_out, int out_size, void* d_ws, size_t ws_size,
                              hipStream_t stream) {
    const float* emb = (const float*)d_in[0];
    const void*  src = d_in[1];
    const void*  tgt = d_in[2];
    // d_in[3] = edge_type_idx (selector; params passed are already the selected ones)
    const float* W1 = (const float*)d_in[4];
    const float* b1 = (const float*)d_in[5];
    const float* W2 = (const float*)d_in[6];
    const float* b2 = (const float*)d_in[7];
    float* out = (float*)d_out;

    const int E  = in_sizes[1];
    const int Nn = in_sizes[0] / HID;

    const size_t uv_bytes = (size_t)Nn * HID * sizeof(short);
    // layout: bpk2 64K | gh 256B | cursor 256B | pad to 64K+4K | U | V | st | ei
    const size_t off_gh   = 65536;
    const size_t off_U    = 65536 + 4096;
    const size_t off_V    = off_U + uv_bytes;
    const size_t off_st   = off_V + uv_bytes;
    const size_t off_ei   = off_st + (size_t)E * 8;
    const size_t need_part = off_ei + (size_t)E * 4;
    const size_t need_uv   = 65536 + 2 * uv_bytes;
    const size_t need_old  = 65536 + (size_t)in_sizes[0] * sizeof(short);

    if (ws_size >= need_part && E >= 4096) {
        short*          bpk2   = (short*)d_ws;
        int*            gh     = (int*)((char*)d_ws + off_gh);      // gh[64] then cursor[64]
        int*            cursor = gh + 64;
        unsigned short* U      = (unsigned short*)((char*)d_ws + off_U);
        unsigned short* Vv     = (unsigned short*)((char*)d_ws + off_V);
        int2*           st     = (int2*)((char*)d_ws + off_st);
        int*            ei     = (int*)((char*)d_ws + off_ei);

        const float bscale = 63.9999f / (float)Nn;

        pack_w1_uv_kernel<<<16, 256, 0, stream>>>(W1, bpk2, gh);   // block 0 zeroes gh+cursor
        hist64_kernel<<<256, 256, 0, stream>>>(src, tgt, E, bscale, gh);
        uv_kernel<<<(Nn + 127) / 128, 512, 0, stream>>>(emb, bpk2, U, Vv, Nn);
        scatter64_kernel<<<(E + 2047) / 2048, 256, 0, stream>>>(
            src, tgt, E, bscale, gh, cursor, st, ei);
        const int per_x = (E / 8 + 4096) / 64 + 2;
        edge_pass_part_kernel<<<per_x * 8, 256, 0, stream>>>(
            U, Vv, st, ei, gh, b1, W2, b2, out, per_x);
        return;
    }

    if (ws_size >= need_uv) {
        short*          bpk2 = (short*)d_ws;
        unsigned short* U    = (unsigned short*)((char*)d_ws + 65536);
        unsigned short* Vv   = (unsigned short*)((char*)d_ws + 65536 + uv_bytes);

        pack_w1_uv_kernel<<<16, 256, 0, stream>>>(W1, bpk2, nullptr);
        uv_kernel<<<(Nn + 127) / 128, 512, 0, stream>>>(emb, bpk2, U, Vv, Nn);
        edge_pass_kernel<<<(E + 63) / 64, 256, 0, stream>>>(U, Vv, src, tgt, b1, W2, b2, out, E);
        return;
    }

    // ---- fallback: R3 gathered-MFMA path
    short* bpk  = (short*)d_ws;
    short* bemb = (short*)((char*)d_ws + 65536);

    int mode;
    if (ws_size >= need_old)        mode = 0;
    else if (ws_size >= 65536)      mode = 1;
    else                            mode = 2;

    if (mode != 2)
        pack_w1_kernel<<<16, 256, 0, stream>>>(W1, bpk);
    if (mode == 0) {
        const int n8 = in_sizes[0] / 8;
        conv_emb_kernel<<<(n8 + 255) / 256, 256, 0, stream>>>(emb, bemb, n8);
    }

    const int grid = (E + 255) / 256;
    if (mode == 0)
        edge_head_kernel<0><<<grid, 512, 0, stream>>>(emb, bemb, src, tgt, W1, b1, W2, b2, bpk, out, E);
    else if (mode == 1)
        edge_head_kernel<1><<<grid, 512, 0, stream>>>(emb, bemb, src, tgt, W1, b1, W2, b2, bpk, out, E);
    else
        edge_head_kernel<2><<<grid, 512, 0, stream>>>(emb, bemb, src, tgt, W1, b1, W2, b2, bpk, out, E);
}

// Round 17
// 145.248 us; speedup vs baseline: 1.8700x; 1.0152x over previous
//
#include <hip/hip_runtime.h>
#include <hip/hip_bf16.h>

#define HID 128

typedef __attribute__((ext_vector_type(8))) short short8;
typedef __attribute__((ext_vector_type(4))) float f32x4;
typedef __attribute__((ext_vector_type(16))) float f32x16;
typedef __attribute__((ext_vector_type(4))) unsigned int u32x4;
typedef __attribute__((ext_vector_type(2))) _Float16 h2;

__device__ __forceinline__ short f2bf(float x) {
    __bf16 b = (__bf16)x;
    return __builtin_bit_cast(short, b);
}

// ===========================================================================
// FACTORED PATH: U = emb@W1[:128], V = emb@W1[128:] (dense per-node GEMM),
// then out[e] = relu(U[src]+V[tgt]+b1)@W2 + b2 (gather + packed-fp16 VALU).
// R17: tgt-partitioned edge pass (proven 79us, FETCH at compulsory floor)
// with a slim prefix: 8-byte packed records (s17|t17|e21), hist fused into
// the W1-pack kernel, scatter LDS 37->17KB.
// ===========================================================================

// ---------------------------------------------------------------------------
// Fused: blocks 0..15 pack W1 halves into 32x32x16 MFMA-B fragment order;
// ALL blocks histogram tgt into 64 buckets (gh pre-zeroed via memset).
// ---------------------------------------------------------------------------
__global__ __launch_bounds__(256) void hist_pack_kernel(
    const float* __restrict__ W1, short* __restrict__ bpk2,
    const void* __restrict__ src_raw, const void* __restrict__ tgt_raw,
    int E, float bscale, int* __restrict__ gh)
{
    const int tid = threadIdx.x;

    if (blockIdx.x < 16) {
        int t = blockIdx.x * 256 + tid;   // 0..4095 = half*2048 + nt*512 + ks*64 + l
        int l    = t & 63;
        int ks   = (t >> 6) & 7;
        int nt   = (t >> 9) & 3;
        int half = t >> 11;
        int k0  = half * 128 + ks * 16 + (l >> 5) * 8;
        int col = nt * 32 + (l & 31);
        short8 v;
#pragma unroll
        for (int j = 0; j < 8; ++j)
            v[j] = f2bf(W1[(k0 + j) * HID + col]);
        *reinterpret_cast<short8*>(&bpk2[t * 8]) = v;
    }

    __shared__ int lh[64];
    if (tid < 64) lh[tid] = 0;
    __syncthreads();

    int i64f = 1;
    {
        const int* s32 = (const int*)src_raw;
#pragma unroll
        for (int i = 1; i < 32; i += 2) i64f &= (s32[i] == 0);
    }
    const int stride = gridDim.x * 256;
    for (int e = blockIdx.x * 256 + tid; e < E; e += stride) {
        int t = i64f ? (int)((const long long*)tgt_raw)[e]
                     : ((const int*)tgt_raw)[e];
        int b = (int)((float)t * bscale);
        b = b < 0 ? 0 : (b > 63 ? 63 : b);
        atomicAdd(&lh[b], 1);
    }
    __syncthreads();
    if (tid < 64 && lh[tid]) atomicAdd(&gh[tid], lh[tid]);
}

// ---------------------------------------------------------------------------
// UV precompute (fp16 output): mfma_f32_32x32x16_bf16, 128 nodes/block.
// ---------------------------------------------------------------------------
__global__ __launch_bounds__(512, 4) void uv_kernel(
    const float* __restrict__ emb,
    const short* __restrict__ bpk2,
    unsigned short* __restrict__ U,
    unsigned short* __restrict__ V,
    int Nn)
{
    __shared__ short lds_b[32768];

    const int tid = threadIdx.x;
    const int l   = tid & 63;
    const int wid = tid >> 6;
    const int wg  = wid >> 1;
    const int wn  = wid & 1;
    const int lc  = l & 31;
    const int hi  = l >> 5;

    {
        const u32x4* g = (const u32x4*)bpk2;
        u32x4* d = (u32x4*)lds_b;
#pragma unroll
        for (int i = 0; i < 8; ++i) d[i * 512 + tid] = g[i * 512 + tid];
    }
    __syncthreads();

    const int base = blockIdx.x * 128 + wg * 32;
    int nr = base + lc;
    if (nr >= Nn) nr = Nn - 1;

    f32x16 accU[2], accV[2];
#pragma unroll
    for (int n = 0; n < 2; ++n) { accU[n] = (f32x16)(0.f); accV[n] = (f32x16)(0.f); }

#pragma unroll
    for (int ks = 0; ks < 8; ++ks) {
        const float* p = emb + (size_t)nr * HID + ks * 16 + hi * 8;
        f32x4 x0 = *reinterpret_cast<const f32x4*>(p);
        f32x4 x1 = *reinterpret_cast<const f32x4*>(p + 4);
        short8 afr;
#pragma unroll
        for (int j = 0; j < 4; ++j) { afr[j] = f2bf(x0[j]); afr[4 + j] = f2bf(x1[j]); }
#pragma unroll
        for (int n = 0; n < 2; ++n) {
            const int nt = wn * 2 + n;
            short8 bU = *reinterpret_cast<const short8*>(&lds_b[(((0 + nt) * 8 + ks) * 64 + l) * 8]);
            short8 bV = *reinterpret_cast<const short8*>(&lds_b[(((4 + nt) * 8 + ks) * 64 + l) * 8]);
            accU[n] = __builtin_amdgcn_mfma_f32_32x32x16_bf16(afr, bU, accU[n], 0, 0, 0);
            accV[n] = __builtin_amdgcn_mfma_f32_32x32x16_bf16(afr, bV, accV[n], 0, 0, 0);
        }
    }

#pragma unroll
    for (int n = 0; n < 2; ++n) {
        const int col = wn * 64 + n * 32 + lc;
#pragma unroll
        for (int r = 0; r < 16; ++r) {
            const int row = (r & 3) + 8 * (r >> 2) + 4 * hi;
            const int node = base + row;
            if (node < Nn) {
                _Float16 hu = (_Float16)accU[n][r];
                _Float16 hv = (_Float16)accV[n][r];
                U[(size_t)node * HID + col] = __builtin_bit_cast(unsigned short, hu);
                V[(size_t)node * HID + col] = __builtin_bit_cast(unsigned short, hv);
            }
        }
    }
}

// ---------------------------------------------------------------------------
// LDS-staged partition scatter with 8-byte packed records:
// rec = e | (s<<21) | (t<<38)   (requires E<2^21, Nn<2^17).
// Wave-parallel scans; bucket recomputed from t in the write loop.
// ---------------------------------------------------------------------------
__global__ __launch_bounds__(256) void scatter64_kernel(
    const void* __restrict__ src_raw, const void* __restrict__ tgt_raw,
    int E, float bscale,
    const int* __restrict__ gh, int* __restrict__ cursor,
    unsigned long long* __restrict__ rec)
{
    __shared__ int lh[64], lh2[64], lo[64], grb[64], go[64];
    __shared__ unsigned long long sR[2048];

    const int tid = threadIdx.x;
    int i64f = 1;
    {
        const int* s32 = (const int*)src_raw;
#pragma unroll
        for (int i = 1; i < 32; i += 2) i64f &= (s32[i] == 0);
    }
    if (tid < 64) { lh[tid] = 0; lh2[tid] = 0; }
    __syncthreads();

    const int base = blockIdx.x * 2048;
    int myS[8], myT[8], myB[8];
#pragma unroll
    for (int k = 0; k < 8; ++k) {
        const int e = base + k * 256 + tid;
        myB[k] = -1;
        if (e < E) {
            int s, t;
            if (i64f) {
                s = (int)((const long long*)src_raw)[e];
                t = (int)((const long long*)tgt_raw)[e];
            } else {
                s = ((const int*)src_raw)[e];
                t = ((const int*)tgt_raw)[e];
            }
            int b = (int)((float)t * bscale);
            b = b < 0 ? 0 : (b > 63 ? 63 : b);
            myS[k] = s; myT[k] = t; myB[k] = b;
            atomicAdd(&lh[b], 1);
        }
    }
    __syncthreads();
    if (tid < 64) {
        int vl = lh[tid], vg = gh[tid];
        int il = vl, ig = vg;
#pragma unroll
        for (int off = 1; off < 64; off <<= 1) {
            int xl = __shfl_up(il, off, 64);
            int xg = __shfl_up(ig, off, 64);
            if (tid >= off) { il += xl; ig += xg; }
        }
        lo[tid] = il - vl;
        go[tid] = ig - vg;
        grb[tid] = (vl > 0) ? atomicAdd(&cursor[tid], vl) : 0;
    }
    __syncthreads();
#pragma unroll
    for (int k = 0; k < 8; ++k) {
        if (myB[k] >= 0) {
            const int b = myB[k];
            const int pl = lo[b] + atomicAdd(&lh2[b], 1);
            sR[pl] = (unsigned long long)(unsigned)(base + k * 256 + tid)
                   | ((unsigned long long)(unsigned)myS[k] << 21)
                   | ((unsigned long long)(unsigned)myT[k] << 38);
        }
    }
    __syncthreads();
    const int total = lo[63] + lh[63];
    for (int i = tid; i < total; i += 256) {
        const unsigned long long r = sR[i];
        const int t = (int)(r >> 38);
        int b = (int)((float)t * bscale);
        b = b < 0 ? 0 : (b > 63 ? 63 : b);
        rec[go[b] + grb[b] + (i - lo[b])] = r;
    }
}

// ---------------------------------------------------------------------------
// Partitioned edge pass: XCD p (blockIdx%8, round-robin dispatch) processes
// edges [off8[p], off8[p+1]); off8 derived in-block from gh by a wave scan.
// One 8B record load per edge; fp16 packed math.
// ---------------------------------------------------------------------------
__global__ __launch_bounds__(256) void edge_pass_part_kernel(
    const unsigned short* __restrict__ U,
    const unsigned short* __restrict__ V,
    const unsigned long long* __restrict__ rec,
    const int* __restrict__ gh,
    const float* __restrict__ b1,
    const float* __restrict__ W2,
    const float* __restrict__ b2,
    float* __restrict__ out,
    int per_x)
{
    __shared__ int sh_off8[9];

    const int tid = threadIdx.x;
    if (tid < 64) {
        int v = gh[tid];
        int inc = v;
#pragma unroll
        for (int off = 1; off < 64; off <<= 1) {
            int x = __shfl_up(inc, off, 64);
            if (tid >= off) inc += x;
        }
        if ((tid & 7) == 0) sh_off8[tid >> 3] = inc - v;
        if (tid == 63) sh_off8[8] = inc;
    }
    __syncthreads();

    const int l   = tid & 63;
    const int wid = tid >> 6;
    const int le  = l >> 4;          // edge slot in group (0..3)
    const int lc  = l & 15;          // col group: cols [lc*8, lc*8+8)
    const int p   = blockIdx.x & 7;  // XCD (round-robin dispatch)
    const int r   = blockIdx.x >> 3;

    const int pbeg = sh_off8[p];
    const int pend = sh_off8[p + 1];

    h2 b1p[4], w2p[4];
    {
        f32x4 a = *reinterpret_cast<const f32x4*>(b1 + lc * 8);
        f32x4 b = *reinterpret_cast<const f32x4*>(b1 + lc * 8 + 4);
        f32x4 c = *reinterpret_cast<const f32x4*>(W2 + lc * 8);
        f32x4 d = *reinterpret_cast<const f32x4*>(W2 + lc * 8 + 4);
#pragma unroll
        for (int j = 0; j < 2; ++j) {
            b1p[0][j] = (_Float16)a[j];     b1p[1][j] = (_Float16)a[2 + j];
            b1p[2][j] = (_Float16)b[j];     b1p[3][j] = (_Float16)b[2 + j];
            w2p[0][j] = (_Float16)c[j];     w2p[1][j] = (_Float16)c[2 + j];
            w2p[2][j] = (_Float16)d[j];     w2p[3][j] = (_Float16)d[2 + j];
        }
    }
    const float b2s = b2[0];
    const h2 zero2 = (h2)((_Float16)0.f);

    for (int base = pbeg + r * 64; base < pend; base += per_x * 64) {
        short8 ub[4], vb[4];
        int oid[4];
        bool live[4];
#pragma unroll
        for (int g = 0; g < 4; ++g) {
            int pos = base + wid * 16 + g * 4 + le;
            live[g] = (pos < pend);
            if (!live[g]) pos = base;
            const unsigned long long rc = rec[pos];
            oid[g] = (int)(rc & 0x1FFFFF);
            const unsigned s = (unsigned)((rc >> 21) & 0x1FFFF);
            const unsigned t = (unsigned)(rc >> 38);
            ub[g] = *reinterpret_cast<const short8*>(U + s * HID + lc * 8);
            vb[g] = *reinterpret_cast<const short8*>(V + t * HID + lc * 8);
        }

#pragma unroll
        for (int g = 0; g < 4; ++g) {
            const unsigned int* uw = (const unsigned int*)&ub[g];
            const unsigned int* vw = (const unsigned int*)&vb[g];
            h2 s2 = zero2;
#pragma unroll
            for (int j = 0; j < 4; ++j) {
                h2 hu = __builtin_bit_cast(h2, uw[j]);
                h2 hv = __builtin_bit_cast(h2, vw[j]);
                h2 h  = hu + hv + b1p[j];
                h = __builtin_elementwise_max(h, zero2);
                s2 = s2 + h * w2p[j];
            }
            float s = (float)s2[0] + (float)s2[1];
#pragma unroll
            for (int w = 1; w < 16; w <<= 1)
                s += __shfl_xor(s, w, 16);
            if (lc == 0 && live[g])
                out[oid[g]] = s + b2s;
        }
    }
}

// ---------------------------------------------------------------------------
// Unsorted edge pass (R12 path, fallback).
// ---------------------------------------------------------------------------
__global__ __launch_bounds__(256) void edge_pass_kernel(
    const unsigned short* __restrict__ U,
    const unsigned short* __restrict__ V,
    const void* __restrict__ src_raw,
    const void* __restrict__ tgt_raw,
    const float* __restrict__ b1,
    const float* __restrict__ W2,
    const float* __restrict__ b2,
    float* __restrict__ out,
    int E)
{
    const int tid = threadIdx.x;
    const int l   = tid & 63;
    const int wid = tid >> 6;
    const int le  = l >> 4;
    const int lc  = l & 15;

    int oddw = 0;
    {
        const int* s32 = (const int*)src_raw;
        if (l < 32) oddw = s32[2 * l + 1];
    }
    const bool i64f = (__ballot(oddw != 0) == 0ULL);

    h2 b1p[4], w2p[4];
    {
        f32x4 a = *reinterpret_cast<const f32x4*>(b1 + lc * 8);
        f32x4 b = *reinterpret_cast<const f32x4*>(b1 + lc * 8 + 4);
        f32x4 c = *reinterpret_cast<const f32x4*>(W2 + lc * 8);
        f32x4 d = *reinterpret_cast<const f32x4*>(W2 + lc * 8 + 4);
#pragma unroll
        for (int j = 0; j < 2; ++j) {
            b1p[0][j] = (_Float16)a[j];     b1p[1][j] = (_Float16)a[2 + j];
            b1p[2][j] = (_Float16)b[j];     b1p[3][j] = (_Float16)b[2 + j];
            w2p[0][j] = (_Float16)c[j];     w2p[1][j] = (_Float16)c[2 + j];
            w2p[2][j] = (_Float16)d[j];     w2p[3][j] = (_Float16)d[2 + j];
        }
    }
    const float b2s = b2[0];
    const h2 zero2 = (h2)((_Float16)0.f);

    const long long ebase = ((long long)blockIdx.x * 4 + wid) * 16;

    short8 ub[4], vb[4];
#pragma unroll
    for (int g = 0; g < 4; ++g) {
        long long e = ebase + g * 4 + le;
        if (e >= E) e = E - 1;
        long long si, ti;
        if (i64f) {
            si = ((const long long*)src_raw)[e];
            ti = ((const long long*)tgt_raw)[e];
        } else {
            si = ((const int*)src_raw)[e];
            ti = ((const int*)tgt_raw)[e];
        }
        ub[g] = *reinterpret_cast<const short8*>(U + (unsigned)si * HID + lc * 8);
        vb[g] = *reinterpret_cast<const short8*>(V + (unsigned)ti * HID + lc * 8);
    }

#pragma unroll
    for (int g = 0; g < 4; ++g) {
        const unsigned int* uw = (const unsigned int*)&ub[g];
        const unsigned int* vw = (const unsigned int*)&vb[g];
        h2 s2 = zero2;
#pragma unroll
        for (int j = 0; j < 4; ++j) {
            h2 hu = __builtin_bit_cast(h2, uw[j]);
            h2 hv = __builtin_bit_cast(h2, vw[j]);
            h2 h  = hu + hv + b1p[j];
            h = __builtin_elementwise_max(h, zero2);
            s2 = s2 + h * w2p[j];
        }
        float s = (float)s2[0] + (float)s2[1];
#pragma unroll
        for (int w = 1; w < 16; w <<= 1)
            s += __shfl_xor(s, w, 16);
        const long long e = ebase + g * 4 + le;
        if (lc == 0 && e < E)
            out[e] = s + b2s;
    }
}

// ===========================================================================
// FALLBACK PATH (R3): MFMA over gathered rows (bf16), for tiny ws.
// ===========================================================================

__global__ void pack_w1_kernel(const float* __restrict__ W1, short* __restrict__ bpk) {
    int t = blockIdx.x * 256 + threadIdx.x;
    int f = (t >> 6) & 7;
    int l = t & 63;
    int n = t >> 9;
    int c = l & 15, kb = l >> 4;
    int k0 = f * 32 + kb * 8;
    short8 v;
#pragma unroll
    for (int j = 0; j < 8; ++j)
        v[j] = f2bf(W1[(k0 + j) * HID + n * 16 + c]);
    *reinterpret_cast<short8*>(&bpk[t * 8]) = v;
}

__global__ __launch_bounds__(256) void conv_emb_kernel(
    const float* __restrict__ emb, short* __restrict__ bemb, int n8) {
    int i = blockIdx.x * 256 + threadIdx.x;
    if (i >= n8) return;
    f32x4 x0 = *reinterpret_cast<const f32x4*>(emb + (size_t)i * 8);
    f32x4 x1 = *reinterpret_cast<const f32x4*>(emb + (size_t)i * 8 + 4);
    short8 v;
#pragma unroll
    for (int j = 0; j < 4; ++j) {
        v[j]     = f2bf(x0[j]);
        v[4 + j] = f2bf(x1[j]);
    }
    *reinterpret_cast<short8*>(&bemb[(size_t)i * 8]) = v;
}

template <int MODE>
__global__ __launch_bounds__(512, 4) void edge_head_kernel(
    const float* __restrict__ emb,
    const short* __restrict__ bemb,
    const void* __restrict__ src_raw,
    const void* __restrict__ tgt_raw,
    const float* __restrict__ W1,
    const float* __restrict__ b1,
    const float* __restrict__ W2,
    const float* __restrict__ b2,
    const short* __restrict__ bpk,
    float* __restrict__ out,
    int E)
{
    __shared__ short lds_b[32768];

    const int tid = threadIdx.x;

    int i64f = 1;
    {
        const int* s32 = (const int*)src_raw;
#pragma unroll
        for (int i = 1; i < 32; i += 2) i64f &= (s32[i] == 0);
    }

    if (MODE != 2) {
        const u32x4* g = (const u32x4*)bpk;
        u32x4* d = (u32x4*)lds_b;
#pragma unroll
        for (int i = 0; i < 8; ++i) d[i * 512 + tid] = g[i * 512 + tid];
    } else {
        for (int i = 0; i < 64; ++i) {
            int idx = i * 512 + tid;
            int col = idx & 127;
            int k   = idx >> 7;
            int n = col >> 4, cc = col & 15;
            int f = k >> 5, kb = (k >> 3) & 3, j = k & 7;
            int l2 = kb * 16 + cc;
            lds_b[(((n * 8 + f) * 64 + l2) << 3) + j] = f2bf(W1[idx]);
        }
    }
    __syncthreads();

    const int l = tid & 63;
    const int wid = tid >> 6;
    const int c = l & 15;
    const int g = l >> 4;
    const long long e0 = (long long)blockIdx.x * 256 + wid * 32;

    unsigned so[2], to[2];
#pragma unroll
    for (int m = 0; m < 2; ++m) {
        long long e = e0 + m * 16 + c;
        if (e >= E) e = E - 1;
        long long si, ti;
        if (i64f) {
            si = ((const long long*)src_raw)[e];
            ti = ((const long long*)tgt_raw)[e];
        } else {
            si = ((const int*)src_raw)[e];
            ti = ((const int*)tgt_raw)[e];
        }
        so[m] = (unsigned)si * HID;
        to[m] = (unsigned)ti * HID;
    }

    f32x4 acc[2][8];
#pragma unroll
    for (int m = 0; m < 2; ++m)
#pragma unroll
        for (int n = 0; n < 8; ++n)
            acc[m][n] = (f32x4){0.f, 0.f, 0.f, 0.f};

    const int koff = g * 8;
#pragma unroll
    for (int f = 0; f < 8; ++f) {
        short8 afr[2];
        const int k0 = (f & 3) * 32 + koff;
#pragma unroll
        for (int m = 0; m < 2; ++m) {
            const unsigned off = (f < 4 ? so[m] : to[m]) + k0;
            if (MODE == 0) {
                afr[m] = *reinterpret_cast<const short8*>(bemb + off);
            } else {
                f32x4 x0 = *reinterpret_cast<const f32x4*>(emb + off);
                f32x4 x1 = *reinterpret_cast<const f32x4*>(emb + off + 4);
                short8 t;
#pragma unroll
                for (int j = 0; j < 4; ++j) {
                    t[j]     = f2bf(x0[j]);
                    t[4 + j] = f2bf(x1[j]);
                }
                afr[m] = t;
            }
        }
#pragma unroll
        for (int n = 0; n < 8; ++n) {
            short8 bfr = *reinterpret_cast<const short8*>(&lds_b[((n * 8 + f) * 64 + l) * 8]);
#pragma unroll
            for (int m = 0; m < 2; ++m)
                acc[m][n] = __builtin_amdgcn_mfma_f32_16x16x32_bf16(afr[m], bfr, acc[m][n], 0, 0, 0);
        }
    }

    float b1v[8], w2v[8];
#pragma unroll
    for (int n = 0; n < 8; ++n) {
        b1v[n] = b1[n * 16 + c];
        w2v[n] = W2[n * 16 + c];
    }
    const float b2s = b2[0];

#pragma unroll
    for (int m = 0; m < 2; ++m) {
        float s[4] = {0.f, 0.f, 0.f, 0.f};
#pragma unroll
        for (int n = 0; n < 8; ++n) {
#pragma unroll
            for (int r = 0; r < 4; ++r)
                s[r] += fmaxf(acc[m][n][r] + b1v[n], 0.f) * w2v[n];
        }
#pragma unroll
        for (int w = 1; w < 16; w <<= 1) {
#pragma unroll
            for (int r = 0; r < 4; ++r)
                s[r] += __shfl_xor(s[r], w, 16);
        }
        if (c == 0) {
            const long long eb = e0 + m * 16 + g * 4;
#pragma unroll
            for (int r = 0; r < 4; ++r)
                if (eb + r < E) out[eb + r] = s[r] + b2s;
        }
    }
}

extern "C" void kernel_launch(void* const* d_in, const int* in_sizes, int n_in,
                              void* d_out, int out_size, void* d_ws, size_t ws_size,
                              hipStream_t stream) {
    const float* emb = (const float*)d_in[0];
    const void*  src = d_in[1];
    const void*  tgt = d_in[2];
    // d_in[3] = edge_type_idx (selector; params passed are already the selected ones)
    const float* W1 = (const float*)d_in[4];
    const float* b1 = (const float*)d_in[5];
    const float* W2 = (const float*)d_in[6];
    const float* b2 = (const float*)d_in[7];
    float* out = (float*)d_out;

    const int E  = in_sizes[1];
    const int Nn = in_sizes[0] / HID;

    const size_t uv_bytes = (size_t)Nn * HID * sizeof(short);
    // layout: bpk2 64K | gh[64]+cursor[64] | pad to 64K+4K | U | V | rec
    const size_t off_gh   = 65536;
    const size_t off_U    = 65536 + 4096;
    const size_t off_V    = off_U + uv_bytes;
    const size_t off_rec  = off_V + uv_bytes;
    const size_t need_part = off_rec + (size_t)E * 8;
    const size_t need_uv   = 65536 + 2 * uv_bytes;
    const size_t need_old  = 65536 + (size_t)in_sizes[0] * sizeof(short);

    const bool packable = (Nn <= (1 << 17)) && (E <= (1 << 21));

    if (ws_size >= need_part && E >= 4096 && packable) {
        short*              bpk2   = (short*)d_ws;
        int*                gh     = (int*)((char*)d_ws + off_gh);
        int*                cursor = gh + 64;
        unsigned short*     U      = (unsigned short*)((char*)d_ws + off_U);
        unsigned short*     Vv     = (unsigned short*)((char*)d_ws + off_V);
        unsigned long long* rec    = (unsigned long long*)((char*)d_ws + off_rec);

        const float bscale = 63.9999f / (float)Nn;

        hipMemsetAsync(gh, 0, 512, stream);
        hist_pack_kernel<<<256, 256, 0, stream>>>(W1, bpk2, src, tgt, E, bscale, gh);
        uv_kernel<<<(Nn + 127) / 128, 512, 0, stream>>>(emb, bpk2, U, Vv, Nn);
        scatter64_kernel<<<(E + 2047) / 2048, 256, 0, stream>>>(
            src, tgt, E, bscale, gh, cursor, rec);
        const int per_x = (E / 8 + 4096) / 64 + 2;
        edge_pass_part_kernel<<<per_x * 8, 256, 0, stream>>>(
            U, Vv, rec, gh, b1, W2, b2, out, per_x);
        return;
    }

    if (ws_size >= need_uv) {
        short*          bpk2 = (short*)d_ws;
        unsigned short* U    = (unsigned short*)((char*)d_ws + 65536);
        unsigned short* Vv   = (unsigned short*)((char*)d_ws + 65536 + uv_bytes);

        hist_pack_kernel<<<16, 256, 0, stream>>>(W1, bpk2, src, tgt, 0, 1.0f, nullptr);
        uv_kernel<<<(Nn + 127) / 128, 512, 0, stream>>>(emb, bpk2, U, Vv, Nn);
        edge_pass_kernel<<<(E + 63) / 64, 256, 0, stream>>>(U, Vv, src, tgt, b1, W2, b2, out, E);
        return;
    }

    // ---- fallback: R3 gathered-MFMA path
    short* bpk  = (short*)d_ws;
    short* bemb = (short*)((char*)d_ws + 65536);

    int mode;
    if (ws_size >= need_old)        mode = 0;
    else if (ws_size >= 65536)      mode = 1;
    else                            mode = 2;

    if (mode != 2)
        pack_w1_kernel<<<16, 256, 0, stream>>>(W1, bpk);
    if (mode == 0) {
        const int n8 = in_sizes[0] / 8;
        conv_emb_kernel<<<(n8 + 255) / 256, 256, 0, stream>>>(emb, bemb, n8);
    }

    const int grid = (E + 255) / 256;
    if (mode == 0)
        edge_head_kernel<0><<<grid, 512, 0, stream>>>(emb, bemb, src, tgt, W1, b1, W2, b2, bpk, out, E);
    else if (mode == 1)
        edge_head_kernel<1><<<grid, 512, 0, stream>>>(emb, bemb, src, tgt, W1, b1, W2, b2, bpk, out, E);
    else
        edge_head_kernel<2><<<grid, 512, 0, stream>>>(emb, bemb, src, tgt, W1, b1, W2, b2, bpk, out, E);
}